// Round 7
// baseline (643.913 us; speedup 1.0000x reference)
//
#include <hip/hip_runtime.h>

typedef __bf16 bf16_t;
typedef __bf16 bf16x4 __attribute__((ext_vector_type(4)));
typedef __bf16 bf16x8 __attribute__((ext_vector_type(8)));
typedef float f32x4 __attribute__((ext_vector_type(4)));

#define GLL16(gp, lp) __builtin_amdgcn_global_load_lds( \
    (__attribute__((address_space(1))) void*)(gp),      \
    (__attribute__((address_space(3))) void*)(lp), 16, 0, 0)

// ---------------------------------------------------------------------------
// 256x256-tile GEMM, BK=32, 4-deep LDS ring, counted vmcnt AND counted lgkm.
//   C[half][M,N] = epi(A[half][M,K] @ W[half][N,K]^T + bias[half])
// 512 threads = 8 waves (2M x 4N); per-wave output 128x64. K=1024 (NT=32).
// LDS 128 KiB: ring of 4 steps x (A 256x32 + B 256x32) bf16 (1 block/CU).
// Cross-phase software pipeline (each MFMA consumes PREV-phase reads):
//  P0: read afH(slot s); barrier; lgkmcnt(4) [waits the 8 older reads only];
//      SB; MFMA m0-3 (afL,bq from prev P1)  -- overlaps afH reads in LDS pipe;
//      vmcnt(4) [slot s+1 staged, counted]; barrier.
//  P1: stage slot s+3; lgkmcnt(0) [= counted: only afH outstanding]; SB;
//      MFMA m4-7 (afH,bq); then issue afL,bq reads of slot s+1 -- they drain
//      under the MFMA pipe + next P0. Reads issued AFTER the MFMA that uses
//      the old register values -> single afL/afH/bq banks, no VGPR growth.
// Hazards: slot s+1 stage-ready = vmcnt(4)+barrier at P0 (outstanding there
// = slots s+1,s+2 only); WAR on re-staged slot s+3==s-1 closed by the two
// lgkm waits of step s-1 + barrier(2) of step s. Tail peels VM4/VM0.
// Swizzle: 16B-granule XOR by row&3, both-sides (staging src + ds_read).
// Epilogue n-innermost (full-line write combining).
// XCD window remap: XCD owns nbyH/8 byh rows x all c, in 8x4 windows.
// EPI: 0 relu->bf16, 1 bias->bf16, 2 sigmoid(U)*v->bf16, 3 bias->f32
// ---------------------------------------------------------------------------
#define STAGE_STEP(NXT) do {                                                 \
    GLL16(asrc0 + koff, &As[(NXT) * 8192 + t * 8]);                          \
    GLL16(asrc1 + koff, &As[(NXT) * 8192 + (t + 512) * 8]);                  \
    GLL16(bsrc0 + koff, &Bs[(NXT) * 8192 + t * 8]);                          \
    GLL16(bsrc1 + koff, &Bs[(NXT) * 8192 + (t + 512) * 8]);                  \
    koff += 32; } while (0)

#define VM4 asm volatile("s_waitcnt vmcnt(4)" ::: "memory")
#define VM0 asm volatile("s_waitcnt vmcnt(0)" ::: "memory")
#define VMN ((void)0)

#define STEP(CUR, NXTS, NXTR, DOSTG, VMW, DONEXT) do {                       \
    /* P0: issue afH(slot CUR); MFMA m0-3 on afL,bq (prev-phase reads) */    \
    _Pragma("unroll") for (int m = 0; m < 4; ++m)                            \
        afH[m] = *(const bf16x8*)(aT + (CUR) * 8192 + (m + 4) * 512);        \
    __builtin_amdgcn_s_barrier();                                            \
    asm volatile("s_waitcnt lgkmcnt(4)" ::: "memory");                       \
    __builtin_amdgcn_sched_barrier(0);                                       \
    __builtin_amdgcn_s_setprio(1);                                           \
    _Pragma("unroll") for (int m = 0; m < 4; ++m)                            \
    _Pragma("unroll") for (int n = 0; n < 4; ++n)                            \
        acc[m][n] = __builtin_amdgcn_mfma_f32_16x16x32_bf16(                 \
            afL[m], bq[n], acc[m][n], 0, 0, 0);                              \
    __builtin_amdgcn_s_setprio(0);                                           \
    VMW;                                                                     \
    __builtin_amdgcn_s_barrier();                                            \
    /* P1: stage slot NXTS; MFMA m4-7 on afH,bq; issue next afL,bq */        \
    if (DOSTG) { STAGE_STEP(NXTS); }                                         \
    asm volatile("s_waitcnt lgkmcnt(0)" ::: "memory");                       \
    __builtin_amdgcn_sched_barrier(0);                                       \
    __builtin_amdgcn_s_setprio(1);                                           \
    _Pragma("unroll") for (int m = 0; m < 4; ++m)                            \
    _Pragma("unroll") for (int n = 0; n < 4; ++n)                            \
        acc[m + 4][n] = __builtin_amdgcn_mfma_f32_16x16x32_bf16(             \
            afH[m], bq[n], acc[m + 4][n], 0, 0, 0);                          \
    __builtin_amdgcn_s_setprio(0);                                           \
    if (DONEXT) {                                                            \
        _Pragma("unroll") for (int n = 0; n < 4; ++n)                        \
            bq[n] = *(const bf16x8*)(bT + (NXTR) * 8192 + n * 512);          \
        _Pragma("unroll") for (int m = 0; m < 4; ++m)                        \
            afL[m] = *(const bf16x8*)(aT + (NXTR) * 8192 + m * 512);         \
    } } while (0)

template<int EPI>
__global__ __launch_bounds__(512, 2)
void gemm256(const bf16_t* __restrict__ A0, const bf16_t* __restrict__ A1, int lda,
             const bf16_t* __restrict__ W0, const bf16_t* __restrict__ W1,
             const float* __restrict__ bias0, const float* __restrict__ bias1,
             const bf16_t* __restrict__ U0, const bf16_t* __restrict__ U1,
             void* __restrict__ C0v, void* __restrict__ C1v, int ldc,
             int K, int nbx, int nbyH, int ctot)
{
    __shared__ bf16_t As[4 * 8192];           // 4 ring steps x 256x32
    __shared__ bf16_t Bs[4 * 8192];

    const int t = threadIdx.x;
    const int w = t >> 6, l = t & 63;
    const int wr = w >> 2, wc = w & 3;        // 2 x 4 wave grid
    const int ro = l & 15, hi = l >> 4;
    const int g0 = hi ^ (ro & 3);             // swizzled granule (4/row)

    // XCD-window remap (gridDim%8==0, nbyH%8==0, ctot%4==0):
    const int xcd   = blockIdx.x & 7;
    const int local = blockIdx.x >> 3;
    const int wpb   = ctot >> 2;              // c-windows per byh stripe
    const int win   = local >> 5;
    const int r5    = local & 31;
    const int strp  = win / wpb;
    const int wcn   = win - strp * wpb;
    const int byh   = xcd * (nbyH >> 3) + strp * 8 + (r5 >> 2);
    const int c     = wcn * 4 + (r5 & 3);
    const int sel   = (c >= nbx) ? 1 : 0;
    const int bx    = c - sel * nbx;

    const bf16_t* A    = sel ? A1 : A0;
    const bf16_t* W    = sel ? W1 : W0;
    const float*  bias = sel ? bias1 : bias0;
    const bf16_t* Up   = sel ? U1 : U0;
    void*         Cp   = sel ? C1v : C0v;

    const bf16_t* Ab = A + (size_t)byh * 256 * lda;
    const bf16_t* Wb = W + (size_t)bx * 256 * K;

    // staging: thread t owns granules t and t+512 of each 256x32 step-tile;
    // granule g: row = g>>2, src col-granule = (g&3) ^ (row&3)  (inverse swz)
    const int srow = t >> 2;
    const int scg  = (t & 3) ^ (srow & 3);
    const bf16_t* asrc0 = Ab + (size_t)srow * lda + scg * 8;
    const bf16_t* asrc1 = asrc0 + (size_t)128 * lda;
    const bf16_t* bsrc0 = Wb + (size_t)srow * K + scg * 8;
    const bf16_t* bsrc1 = bsrc0 + (size_t)128 * K;
    int koff = 0;

    const bf16_t* aT = As + (wr * 128 + ro) * 32 + g0 * 8;
    const bf16_t* bT = Bs + (wc * 64 + ro) * 32 + g0 * 8;

    f32x4 acc[8][4] = {};
    bf16x8 bq[4];
    bf16x8 afL[4], afH[4];

    // prologue: stage slots 0,1,2; vmcnt(8) -> slot 0 ready; read its afL,bq
    STAGE_STEP(0);
    STAGE_STEP(1);
    STAGE_STEP(2);
    asm volatile("s_waitcnt vmcnt(8)" ::: "memory");
    __builtin_amdgcn_s_barrier();
#pragma unroll
    for (int n = 0; n < 4; ++n)
        bq[n] = *(const bf16x8*)(bT + n * 512);
#pragma unroll
    for (int m = 0; m < 4; ++m)
        afL[m] = *(const bf16x8*)(aT + m * 512);

    // NT = 32 steps (K must be 1024). Main: 28 steps; tail: 4 peeled.
#pragma unroll 1
    for (int it = 0; it < 7; ++it) {
        STEP(0, 3, 1, true, VM4, true);
        STEP(1, 0, 2, true, VM4, true);
        STEP(2, 1, 3, true, VM4, true);
        STEP(3, 2, 0, true, VM4, true);
    }
    STEP(0, 3, 1, true,  VM4, true);          // s=28, stages slot 31
    STEP(1, 0, 2, false, VM4, true);          // s=29
    STEP(2, 1, 3, false, VM0, true);          // s=30 (slot 31 must be ready)
    STEP(3, 2, 0, false, VMN, false);         // s=31

    // epilogue: C/D frag layout col=lane&15, row=(lane>>4)*4+j  [guide m89]
    const int rbase = byh * 256 + wr * 128 + (hi << 2);
    const int cbase = bx * 256 + wc * 64 + ro;
    float bc[4];
#pragma unroll
    for (int n = 0; n < 4; ++n) bc[n] = bias[cbase + n * 16];
#pragma unroll
    for (int m = 0; m < 8; ++m) {
#pragma unroll
        for (int j = 0; j < 4; ++j) {
            const int row = rbase + m * 16 + j;
            const size_t off = (size_t)row * ldc + cbase;
#pragma unroll
            for (int n = 0; n < 4; ++n) {
                float v = acc[m][n][j] + bc[n];
                if (EPI == 0) v = fmaxf(v, 0.0f);
                if (EPI == 2) {
                    const float u = (float)Up[off + n * 16];
                    v *= 1.0f / (1.0f + __expf(-u));
                }
                if (EPI == 3) ((float*)Cp)[off + n * 16] = v;
                else          ((bf16_t*)Cp)[off + n * 16] = (bf16_t)v;
            }
        }
    }
}

// ---------------------------------------------------------------------------
// Small 128x128-tile GEMM (r1 structure) for the Wo@Wv weight compose.
// C[M,N](bf16) = A[M,K] @ W[N,K]^T, no bias. Grid (N/128, M/128).
// ---------------------------------------------------------------------------
__global__ __launch_bounds__(256, 2)
void gemm_small_bt(const bf16_t* __restrict__ A, int lda,
                   const bf16_t* __restrict__ W,
                   bf16_t* __restrict__ C, int ldc, int K)
{
    __shared__ bf16_t As[128 * 64];
    __shared__ bf16_t Bs[128 * 64];
    const int t = threadIdx.x;
    const int w = t >> 6, l = t & 63;
    const int wr = w >> 1, wc = w & 1;

    const bf16_t* Ab = A + (size_t)blockIdx.y * 128 * lda;
    const bf16_t* Wb = W + (size_t)blockIdx.x * 128 * K;

    const bf16_t* asrc[4];
    const bf16_t* bsrc[4];
#pragma unroll
    for (int r = 0; r < 4; ++r) {
        const int seg = r * 256 + t;
        asrc[r] = Ab + (size_t)(seg >> 3) * lda + (seg & 7) * 8;
        bsrc[r] = Wb + (size_t)(seg >> 3) * K   + (seg & 7) * 8;
    }

    f32x4 acc[4][4] = {};

    for (int kt = 0; kt < K; kt += 64) {
#pragma unroll
        for (int r = 0; r < 4; ++r) {
            GLL16(asrc[r], As + (r * 256 + w * 64) * 8);
            GLL16(bsrc[r], Bs + (r * 256 + w * 64) * 8);
            asrc[r] += 64;
            bsrc[r] += 64;
        }
        __syncthreads();
#pragma unroll
        for (int kk = 0; kk < 2; ++kk) {
            const int ro = l & 15;
            const int ko = kk * 32 + (l >> 4) * 8;
            bf16x8 af[4], bqv[4];
#pragma unroll
            for (int m = 0; m < 4; ++m)
                af[m] = *(const bf16x8*)(As + (wr * 64 + m * 16 + ro) * 64 + ko);
#pragma unroll
            for (int n = 0; n < 4; ++n)
                bqv[n] = *(const bf16x8*)(Bs + (wc * 64 + n * 16 + ro) * 64 + ko);
#pragma unroll
            for (int m = 0; m < 4; ++m)
#pragma unroll
                for (int n = 0; n < 4; ++n)
                    acc[m][n] = __builtin_amdgcn_mfma_f32_16x16x32_bf16(
                        af[m], bqv[n], acc[m][n], 0, 0, 0);
        }
        __syncthreads();
    }

    const int rbase = blockIdx.y * 128 + wr * 64 + ((l >> 4) << 2);
    const int cbase = blockIdx.x * 128 + wc * 64 + (l & 15);
#pragma unroll
    for (int m = 0; m < 4; ++m)
#pragma unroll
        for (int j = 0; j < 4; ++j) {
            const int row = rbase + m * 16 + j;
#pragma unroll
            for (int n = 0; n < 4; ++n)
                C[(size_t)row * ldc + cbase + n * 16] = (bf16_t)acc[m][n][j];
        }
}

// ---------------------------------------------------------------------------
struct WSrcs { const float* p[9]; };

__global__ __launch_bounds__(256)
void cast_weights(WSrcs srcs, bf16_t* __restrict__ dst)
{
    const int region = blockIdx.x >> 10;
    const float* src = srcs.p[region];
    const size_t base = (size_t)(blockIdx.x & 1023) * 1024 + threadIdx.x * 4;
    const float4 f = *(const float4*)(src + base);
    bf16x4 h = {(bf16_t)f.x, (bf16_t)f.y, (bf16_t)f.z, (bf16_t)f.w};
    *(bf16x4*)(dst + ((size_t)region << 20) + base) = h;
}

// Wv[m][k] (f32) -> WvT[k][m] (bf16); 64x64 tiles via padded LDS.
__global__ __launch_bounds__(256)
void transpose_cast(const float* __restrict__ src, bf16_t* __restrict__ dst)
{
    __shared__ bf16_t tile[64][65];
    const int bm = blockIdx.y * 64, bk = blockIdx.x * 64;
    const int t = threadIdx.x;
#pragma unroll
    for (int s = 0; s < 4; ++s) {
        const int r = s * 16 + (t >> 4);
        const int c = (t & 15) * 4;
        const float4 f = *(const float4*)(src + (size_t)(bm + r) * 1024 + bk + c);
        tile[r][c] = (bf16_t)f.x; tile[r][c + 1] = (bf16_t)f.y;
        tile[r][c + 2] = (bf16_t)f.z; tile[r][c + 3] = (bf16_t)f.w;
    }
    __syncthreads();
#pragma unroll
    for (int s = 0; s < 4; ++s) {
        const int k = s * 16 + (t >> 4);
        const int m = (t & 15) * 4;
        bf16x4 v = {tile[m][k], tile[m + 1][k], tile[m + 2][k], tile[m + 3][k]};
        *(bf16x4*)(dst + (size_t)(bk + k) * 1024 + bm + m) = v;
    }
}

// bvo[j] = dot(Wo[j,:], bv) + bo[j]
__global__ __launch_bounds__(256)
void bias_compose(const float* __restrict__ Wo, const float* __restrict__ bv,
                  const float* __restrict__ bo, float* __restrict__ bvo)
{
    const int j = blockIdx.x, t = threadIdx.x;
    __shared__ float ws4[4];
    const float* wr = Wo + (size_t)j * 1024;
    float s = 0.0f;
#pragma unroll
    for (int i = 0; i < 4; ++i) s += wr[t + i * 256] * bv[t + i * 256];
#pragma unroll
    for (int o = 32; o > 0; o >>= 1) s += __shfl_down(s, o);
    if ((t & 63) == 0) ws4[t >> 6] = s;
    __syncthreads();
    if (t == 0) bvo[j] = ws4[0] + ws4[1] + ws4[2] + ws4[3] + bo[j];
}

__global__ __launch_bounds__(256)
void cast_act(const float* __restrict__ src, bf16_t* __restrict__ dst)
{
    const size_t i = ((size_t)blockIdx.x * 256 + threadIdx.x) * 4;
    const float4 f = *(const float4*)(src + i);
    bf16x4 h = {(bf16_t)f.x, (bf16_t)f.y, (bf16_t)f.z, (bf16_t)f.w};
    *(bf16x4*)(dst + i) = h;
}

__global__ __launch_bounds__(256)
void concat_bias(const float* __restrict__ a, const float* __restrict__ b,
                 float* __restrict__ dst)
{
    const int i = blockIdx.x * 256 + threadIdx.x;
    if (i < 1024) dst[i] = a[i];
    else if (i < 2048) dst[i] = b[i - 1024];
}

// ---------------------------------------------------------------------------
// One block per row: dual l2norm + sigmoid gate + exact top-80 (radix select
// on abs bits, stable lowest-index tie-break) + sparse write + visual concat.
// Scans are wave-level shfl_up (2 barriers/pass instead of 16).
// ---------------------------------------------------------------------------
__global__ __launch_bounds__(256)
void finalize_topk(float* __restrict__ AgF,      // OUT2: in Ag, out final
                   float* __restrict__ AlF,      // OUT3: in Al, out f2
                   const float* __restrict__ VIS,
                   float* __restrict__ O1)
{
    const int row = blockIdx.x, t = threadIdx.x;
    __shared__ int bins[256];
    __shared__ float wred[8];
    __shared__ int wsum[4];
    __shared__ int s_sel, s_kk;

    float* agp = AgF + (size_t)row * 1024 + t * 4;
    float* alp = AlF + (size_t)row * 1024 + t * 4;
    const float4 a4 = *(const float4*)agp;
    const float4 l4 = *(const float4*)alp;
    float av[4] = {a4.x, a4.y, a4.z, a4.w};
    float lv[4] = {l4.x, l4.y, l4.z, l4.w};
    float sa = 0.0f, sb = 0.0f;
#pragma unroll
    for (int j = 0; j < 4; ++j) { sa += av[j] * av[j]; sb += lv[j] * lv[j]; }
#pragma unroll
    for (int o = 32; o > 0; o >>= 1) {
        sa += __shfl_down(sa, o);
        sb += __shfl_down(sb, o);
    }
    if ((t & 63) == 0) { wred[t >> 6] = sa; wred[4 + (t >> 6)] = sb; }
    __syncthreads();
    const float sca = 1.0f / fmaxf(sqrtf(wred[0] + wred[1] + wred[2] + wred[3]), 1e-12f);
    const float scl = 1.0f / fmaxf(sqrtf(wred[4] + wred[5] + wred[6] + wred[7]), 1e-12f);

    float fv[4], f2v[4];
    unsigned ab[4];
#pragma unroll
    for (int j = 0; j < 4; ++j) {
        const float f2 = lv[j] * scl;
        const float f1 = av[j] * sca;
        const float fin = f2 / (1.0f + __expf(-f1));   // sigmoid(f1)*f2
        f2v[j] = f2; fv[j] = fin;
        ab[j] = __float_as_uint(fin) & 0x7fffffffu;
    }
    *(float4*)alp = make_float4(f2v[0], f2v[1], f2v[2], f2v[3]);
    *(float4*)agp = make_float4(fv[0], fv[1], fv[2], fv[3]);

    const float* vr = VIS + (size_t)row * 2048;
    float* o1r = O1 + (size_t)row * 3072;
    *(float4*)(o1r + t * 4)        = *(const float4*)(vr + t * 4);
    *(float4*)(o1r + 1024 + t * 4) = *(const float4*)(vr + 1024 + t * 4);

    // --- radix select: exact bits of the 80th-largest |fin| ---
    unsigned pref = 0u, msk = 0u;
    int kk = 80;
    for (int bp = 3; bp >= 0; --bp) {
        bins[t] = 0;
        __syncthreads();
#pragma unroll
        for (int j = 0; j < 4; ++j)
            if ((ab[j] & msk) == pref)
                atomicAdd(&bins[(ab[j] >> (bp * 8)) & 255], 1);
        __syncthreads();
        const int x = bins[t];
        int p = x;
#pragma unroll
        for (int o = 1; o < 64; o <<= 1) {
            const int y = __shfl_up(p, o);
            if ((t & 63) >= o) p += y;
        }
        if ((t & 63) == 63) wsum[t >> 6] = p;
        __syncthreads();
        const int tot = wsum[0] + wsum[1] + wsum[2] + wsum[3];
        int off = 0;
        if ((t >> 6) > 0) off += wsum[0];
        if ((t >> 6) > 1) off += wsum[1];
        if ((t >> 6) > 2) off += wsum[2];
        p += off;                              // inclusive prefix over 256
        const int Sme = tot - p + x;           // suffix sum incl. bin t
        const int Snx = tot - p;               // suffix sum from bin t+1
        if (Sme >= kk && Snx < kk) { s_sel = t; s_kk = kk - Snx; }
        __syncthreads();
        pref |= (unsigned)s_sel << (bp * 8);
        msk  |= 0xFFu << (bp * 8);
        kk = s_kk;
        __syncthreads();
    }

    // stable tie-break: keep first kk elements equal to threshold (index order)
    int ec = 0;
#pragma unroll
    for (int j = 0; j < 4; ++j) ec += (ab[j] == pref) ? 1 : 0;
    int pe = ec;
#pragma unroll
    for (int o = 1; o < 64; o <<= 1) {
        const int y = __shfl_up(pe, o);
        if ((t & 63) >= o) pe += y;
    }
    if ((t & 63) == 63) wsum[t >> 6] = pe;
    __syncthreads();
    int off2 = 0;
    if ((t >> 6) > 0) off2 += wsum[0];
    if ((t >> 6) > 1) off2 += wsum[1];
    if ((t >> 6) > 2) off2 += wsum[2];
    int excl = pe + off2 - ec;
#pragma unroll
    for (int j = 0; j < 4; ++j) {
        const bool eq = (ab[j] == pref);
        const bool kp = (ab[j] > pref) || (eq && (excl < kk));
        o1r[2048 + t * 4 + j] = kp ? fv[j] : 0.0f;
        if (eq) ++excl;
    }
}

// ---------------------------------------------------------------------------
extern "C" void kernel_launch(void* const* d_in, const int* in_sizes, int n_in,
                              void* d_out, int out_size, void* d_ws, size_t ws_size,
                              hipStream_t stream)
{
    const float* SG   = (const float*)d_in[0];
    const float* SL   = (const float*)d_in[1];
    const float* VIS  = (const float*)d_in[2];
    const float* Wgu1 = (const float*)d_in[3];
    const float* bgu1 = (const float*)d_in[4];
    const float* Wgu2 = (const float*)d_in[5];  const float* bgu2 = (const float*)d_in[6];
    const float* Wgd1 = (const float*)d_in[7];  const float* bgd1 = (const float*)d_in[8];
    const float* Wgd2 = (const float*)d_in[9];  const float* bgd2 = (const float*)d_in[10];
    const float* Wlu1 = (const float*)d_in[11]; const float* blu1 = (const float*)d_in[12];
    const float* Wlu2 = (const float*)d_in[13]; const float* blu2 = (const float*)d_in[14];
    const float* Wld1 = (const float*)d_in[15]; const float* bld1 = (const float*)d_in[16];
    const float* Wld2 = (const float*)d_in[17]; const float* bld2 = (const float*)d_in[18];
    const float* Wo   = (const float*)d_in[19]; const float* bo   = (const float*)d_in[20];
    const float* Win  = (const float*)d_in[21]; const float* bin_ = (const float*)d_in[22];
    const float* Wv = Win + (size_t)2 * 1024 * 1024;   // Win[2E:]
    const float* bv = bin_ + 2048;

    float* OUT1 = (float*)d_out;                         // B x 3072
    float* OUT2 = OUT1 + (size_t)16384 * 3072;           // B x 1024 (final)
    float* OUT3 = OUT2 + (size_t)16384 * 1024;           // B x 1024 (f2)

    // ws: bf16 weights (8 MLP + Wo + composed Wvo) + biases  (~21 MB)
    char* ws = (char*)d_ws;
    bf16_t* Wbf  = (bf16_t*)ws;                          // 8 x 1M (MLP)
    bf16_t* Wo_b = Wbf + (size_t)8 * 1048576;            // [16,18) MB
    bf16_t* Wvo  = Wbf + (size_t)9 * 1048576;            // [18,20) MB
    float*  bb   = (float*)(ws + 20971520);              // 4096 f32
    float*  bvo  = bb + 4096;                            // 1024 f32

    // scratch inside d_out (320 MiB), lifetime-checked (see r2/r5 notes)
    bf16_t* X   = (bf16_t*)d_out;
    bf16_t* Y   = X + (size_t)16384 * 1024;
    bf16_t* Ug  = (bf16_t*)((char*)d_out + 67108864);
    bf16_t* Ul  = (bf16_t*)((char*)d_out + 100663296);
    bf16_t* H1g = (bf16_t*)((char*)d_out + 134217728);
    bf16_t* H1l = (bf16_t*)((char*)d_out + 201326592);
    bf16_t* WvT = H1g;                                   // transient, pre-D1

    WSrcs srcs;
    srcs.p[0] = Wgu1; srcs.p[1] = Wgd1; srcs.p[2] = Wlu1; srcs.p[3] = Wld1;
    srcs.p[4] = Wgu2; srcs.p[5] = Wgd2; srcs.p[6] = Wlu2; srcs.p[7] = Wld2;
    srcs.p[8] = Wo;

    cast_weights<<<9216, 256, 0, stream>>>(srcs, Wbf);
    transpose_cast<<<dim3(16, 16), 256, 0, stream>>>(Wv, WvT);
    concat_bias<<<8, 256, 0, stream>>>(bgu1, bgd1, bb);
    concat_bias<<<8, 256, 0, stream>>>(blu1, bld1, bb + 2048);
    bias_compose<<<1024, 256, 0, stream>>>(Wo, bv, bo, bvo);
    cast_act<<<16384, 256, 0, stream>>>(SG, X);
    cast_act<<<16384, 256, 0, stream>>>(SL, Y);

    // Wvo[n][k] = sum_m Wo[n][m] * Wv[m][k]  (= Wo @ Wv), bf16
    gemm_small_bt<<<dim3(8, 8), 256, 0, stream>>>(Wo_b, 1024, WvT, Wvo, 1024, 1024);

    bf16_t* Wg1   = Wbf;                                 // [Wgu1;Wgd1] 2048x1024
    bf16_t* Wl1   = Wbf + (size_t)2 * 1048576;           // [Wlu1;Wld1]
    bf16_t* Wgu2b = Wbf + (size_t)4 * 1048576;
    bf16_t* Wgd2b = Wbf + (size_t)5 * 1048576;
    bf16_t* Wlu2b = Wbf + (size_t)6 * 1048576;
    bf16_t* Wld2b = Wbf + (size_t)7 * 1048576;

    // D1: h1 = relu([X;Y] @ [W?u1;W?d1]^T + b), per-half weights. N=2048.
    gemm256<0><<<1024, 512, 0, stream>>>(X, Y, 1024, Wg1, Wl1, bb, bb + 2048,
                                         nullptr, nullptr, H1g, H1l, 2048, 1024, 8, 64, 16);
    // D2: U = h1[:, :1024] @ W?u2^T + b  (gate pre-act)
    gemm256<1><<<512, 512, 0, stream>>>(H1g, H1l, 2048, Wgu2b, Wlu2b, bgu2, blu2,
                                        nullptr, nullptr, Ug, Ul, 1024, 1024, 4, 64, 8);
    // D3: s? = sigmoid(U) * (h1[:, 1024:] @ W?d2^T + b)  -> X, Y
    gemm256<2><<<512, 512, 0, stream>>>(H1g + 1024, H1l + 1024, 2048, Wgd2b, Wld2b,
                                        bgd2, bld2, Ug, Ul, X, Y, 1024, 1024, 4, 64, 8);
    // D45: pre-norm attn_out = [sg;sl] @ Wvo^T + bvo -> OUT2/OUT3 (M=32768)
    gemm256<3><<<512, 512, 0, stream>>>(X, X, 1024, Wvo, Wvo, bvo, bvo,
                                        nullptr, nullptr, OUT2, OUT2, 1024, 1024, 4, 128, 4);

    finalize_topk<<<16384, 256, 0, stream>>>(OUT2, OUT3, VIS, OUT1);
}

// Round 8
// 596.472 us; speedup vs baseline: 1.0795x; 1.0795x over previous
//
#include <hip/hip_runtime.h>

typedef __bf16 bf16_t;
typedef __bf16 bf16x4 __attribute__((ext_vector_type(4)));
typedef __bf16 bf16x8 __attribute__((ext_vector_type(8)));
typedef float f32x4 __attribute__((ext_vector_type(4)));

#define GLL16(gp, lp) __builtin_amdgcn_global_load_lds( \
    (__attribute__((address_space(1))) void*)(gp),      \
    (__attribute__((address_space(3))) void*)(lp), 16, 0, 0)

// ---------------------------------------------------------------------------
// 128x128-tile GEMM, m97 structure: BK=64, 256 threads (4 waves 2x2),
// single-buffered 32 KiB LDS, 2 barriers/K-tile -> 5 blocks/CU resident.
// Cross-block wave overlap covers the staging drain (m97/m114 mechanism).
//   C[half][M,N] = epi(A[half][M,K] @ W[half][N,K]^T + bias[half])
// Swizzle: 16B-granule XOR by row&7 on BOTH global source and ds_read
// (involution) -> quarter-wave 2 lanes/bank = conflict-free.
// Epilogue n-innermost (full-line write combining).
// XCD window remap: XCD owns nbyH/8 byh rows; 8-byh x 4-c windows keep
// A-stripe (2 MB) + B slice (1 MB) in the XCD's L2.
// EPI: 0 relu->bf16, 1 bias->bf16, 2 sigmoid(U)*v->bf16, 3 bias->f32
// ---------------------------------------------------------------------------
template<int EPI>
__global__ __launch_bounds__(256, 2)
void gemm128(const bf16_t* __restrict__ A0, const bf16_t* __restrict__ A1, int lda,
             const bf16_t* __restrict__ W0, const bf16_t* __restrict__ W1,
             const float* __restrict__ bias0, const float* __restrict__ bias1,
             const bf16_t* __restrict__ U0, const bf16_t* __restrict__ U1,
             void* __restrict__ C0v, void* __restrict__ C1v, int ldc,
             int K, int nbx, int nbyH, int ctot)
{
    __shared__ bf16_t As[128 * 64];
    __shared__ bf16_t Bs[128 * 64];

    const int t = threadIdx.x;
    const int w = t >> 6, l = t & 63;
    const int wr = w >> 1, wc = w & 1;        // 2 x 2 wave grid
    const int ro = l & 15, hi = l >> 4;
    const int swz = ro & 7;                   // = row&7 for all frag rows

    // XCD-window remap (gridDim%8==0, nbyH%8==0, ctot%4==0)
    const int xcd   = blockIdx.x & 7;
    const int local = blockIdx.x >> 3;
    const int wpb   = ctot >> 2;              // c-windows per byh stripe
    const int win   = local >> 5;
    const int r5    = local & 31;
    const int strp  = win / wpb;
    const int wcn   = win - strp * wpb;
    const int byh   = xcd * (nbyH >> 3) + strp * 8 + (r5 >> 2);
    const int c     = wcn * 4 + (r5 & 3);
    const int sel   = (c >= nbx) ? 1 : 0;
    const int bx    = c - sel * nbx;

    const bf16_t* A    = sel ? A1 : A0;
    const bf16_t* W    = sel ? W1 : W0;
    const float*  bias = sel ? bias1 : bias0;
    const bf16_t* Up   = sel ? U1 : U0;
    void*         Cp   = sel ? C1v : C0v;

    const bf16_t* Ab = A + (size_t)byh * 128 * lda;
    const bf16_t* Wb = W + (size_t)bx * 128 * K;

    // pre-swizzled per-lane global sources (inverse of the ds_read swizzle):
    // tile granule g (16B): row = g>>3, src col-granule = (g&7) ^ (row&7)
    const bf16_t* asrc[4];
    const bf16_t* bsrc[4];
#pragma unroll
    for (int r = 0; r < 4; ++r) {
        const int g   = r * 256 + t;          // 1024 granules per 128x64 tile
        const int row = g >> 3;
        const int cg  = (g & 7) ^ (row & 7);
        asrc[r] = Ab + (size_t)row * lda + cg * 8;
        bsrc[r] = Wb + (size_t)row * K   + cg * 8;
    }

    f32x4 acc[4][4] = {};

    for (int kt = 0; kt < K; kt += 64) {
#pragma unroll
        for (int r = 0; r < 4; ++r) {
            GLL16(asrc[r], As + (r * 256 + w * 64) * 8);
            GLL16(bsrc[r], Bs + (r * 256 + w * 64) * 8);
            asrc[r] += 64;
            bsrc[r] += 64;
        }
        __syncthreads();   // compiler emits vmcnt(0) drain; 5 blocks/CU overlap it
#pragma unroll
        for (int kk = 0; kk < 2; ++kk) {
            const int go = (((kk << 2) | hi) ^ swz) * 8;   // swizzled granule
            bf16x8 af[4], bq[4];
#pragma unroll
            for (int m = 0; m < 4; ++m)
                af[m] = *(const bf16x8*)(As + (wr * 64 + m * 16 + ro) * 64 + go);
#pragma unroll
            for (int n = 0; n < 4; ++n)
                bq[n] = *(const bf16x8*)(Bs + (wc * 64 + n * 16 + ro) * 64 + go);
#pragma unroll
            for (int m = 0; m < 4; ++m)
#pragma unroll
                for (int n = 0; n < 4; ++n)
                    acc[m][n] = __builtin_amdgcn_mfma_f32_16x16x32_bf16(
                        af[m], bq[n], acc[m][n], 0, 0, 0);
        }
        __syncthreads();
    }

    // epilogue: C/D frag layout col=lane&15, row=(lane>>4)*4+j  [guide m89]
    // n-innermost: each line gets its 4 stores back-to-back (write combining).
    const int rbase = byh * 128 + wr * 64 + (hi << 2);
    const int cbase = bx * 128 + wc * 64 + ro;
    float bc[4];
#pragma unroll
    for (int n = 0; n < 4; ++n) bc[n] = bias[cbase + n * 16];
#pragma unroll
    for (int m = 0; m < 4; ++m) {
#pragma unroll
        for (int j = 0; j < 4; ++j) {
            const int row = rbase + m * 16 + j;
            const size_t off = (size_t)row * ldc + cbase;
#pragma unroll
            for (int n = 0; n < 4; ++n) {
                float v = acc[m][n][j] + bc[n];
                if (EPI == 0) v = fmaxf(v, 0.0f);
                if (EPI == 2) {
                    const float u = (float)Up[off + n * 16];
                    v *= 1.0f / (1.0f + __expf(-u));
                }
                if (EPI == 3) ((float*)Cp)[off + n * 16] = v;
                else          ((bf16_t*)Cp)[off + n * 16] = (bf16_t)v;
            }
        }
    }
}

// ---------------------------------------------------------------------------
// Small 128x128-tile GEMM for the Wo@Wv weight compose.
// C[M,N](bf16) = A[M,K] @ W[N,K]^T, no bias. Grid (N/128, M/128).
// ---------------------------------------------------------------------------
__global__ __launch_bounds__(256, 2)
void gemm_small_bt(const bf16_t* __restrict__ A, int lda,
                   const bf16_t* __restrict__ W,
                   bf16_t* __restrict__ C, int ldc, int K)
{
    __shared__ bf16_t As[128 * 64];
    __shared__ bf16_t Bs[128 * 64];
    const int t = threadIdx.x;
    const int w = t >> 6, l = t & 63;
    const int wr = w >> 1, wc = w & 1;

    const bf16_t* Ab = A + (size_t)blockIdx.y * 128 * lda;
    const bf16_t* Wb = W + (size_t)blockIdx.x * 128 * K;

    const bf16_t* asrc[4];
    const bf16_t* bsrc[4];
#pragma unroll
    for (int r = 0; r < 4; ++r) {
        const int seg = r * 256 + t;
        asrc[r] = Ab + (size_t)(seg >> 3) * lda + (seg & 7) * 8;
        bsrc[r] = Wb + (size_t)(seg >> 3) * K   + (seg & 7) * 8;
    }

    f32x4 acc[4][4] = {};

    for (int kt = 0; kt < K; kt += 64) {
#pragma unroll
        for (int r = 0; r < 4; ++r) {
            GLL16(asrc[r], As + (r * 256 + w * 64) * 8);
            GLL16(bsrc[r], Bs + (r * 256 + w * 64) * 8);
            asrc[r] += 64;
            bsrc[r] += 64;
        }
        __syncthreads();
#pragma unroll
        for (int kk = 0; kk < 2; ++kk) {
            const int ro = l & 15;
            const int ko = kk * 32 + (l >> 4) * 8;
            bf16x8 af[4], bqv[4];
#pragma unroll
            for (int m = 0; m < 4; ++m)
                af[m] = *(const bf16x8*)(As + (wr * 64 + m * 16 + ro) * 64 + ko);
#pragma unroll
            for (int n = 0; n < 4; ++n)
                bqv[n] = *(const bf16x8*)(Bs + (wc * 64 + n * 16 + ro) * 64 + ko);
#pragma unroll
            for (int m = 0; m < 4; ++m)
#pragma unroll
                for (int n = 0; n < 4; ++n)
                    acc[m][n] = __builtin_amdgcn_mfma_f32_16x16x32_bf16(
                        af[m], bqv[n], acc[m][n], 0, 0, 0);
        }
        __syncthreads();
    }

    const int rbase = blockIdx.y * 128 + wr * 64 + ((l >> 4) << 2);
    const int cbase = blockIdx.x * 128 + wc * 64 + (l & 15);
#pragma unroll
    for (int m = 0; m < 4; ++m)
#pragma unroll
        for (int j = 0; j < 4; ++j) {
            const int row = rbase + m * 16 + j;
#pragma unroll
            for (int n = 0; n < 4; ++n)
                C[(size_t)row * ldc + cbase + n * 16] = (bf16_t)acc[m][n][j];
        }
}

// ---------------------------------------------------------------------------
struct WSrcs { const float* p[9]; };

__global__ __launch_bounds__(256)
void cast_weights(WSrcs srcs, bf16_t* __restrict__ dst)
{
    const int region = blockIdx.x >> 10;
    const float* src = srcs.p[region];
    const size_t base = (size_t)(blockIdx.x & 1023) * 1024 + threadIdx.x * 4;
    const float4 f = *(const float4*)(src + base);
    bf16x4 h = {(bf16_t)f.x, (bf16_t)f.y, (bf16_t)f.z, (bf16_t)f.w};
    *(bf16x4*)(dst + ((size_t)region << 20) + base) = h;
}

// Wv[m][k] (f32) -> WvT[k][m] (bf16); 64x64 tiles via padded LDS.
__global__ __launch_bounds__(256)
void transpose_cast(const float* __restrict__ src, bf16_t* __restrict__ dst)
{
    __shared__ bf16_t tile[64][65];
    const int bm = blockIdx.y * 64, bk = blockIdx.x * 64;
    const int t = threadIdx.x;
#pragma unroll
    for (int s = 0; s < 4; ++s) {
        const int r = s * 16 + (t >> 4);
        const int c = (t & 15) * 4;
        const float4 f = *(const float4*)(src + (size_t)(bm + r) * 1024 + bk + c);
        tile[r][c] = (bf16_t)f.x; tile[r][c + 1] = (bf16_t)f.y;
        tile[r][c + 2] = (bf16_t)f.z; tile[r][c + 3] = (bf16_t)f.w;
    }
    __syncthreads();
#pragma unroll
    for (int s = 0; s < 4; ++s) {
        const int k = s * 16 + (t >> 4);
        const int m = (t & 15) * 4;
        bf16x4 v = {tile[m][k], tile[m + 1][k], tile[m + 2][k], tile[m + 3][k]};
        *(bf16x4*)(dst + (size_t)(bk + k) * 1024 + bm + m) = v;
    }
}

// bvo[j] = dot(Wo[j,:], bv) + bo[j]
__global__ __launch_bounds__(256)
void bias_compose(const float* __restrict__ Wo, const float* __restrict__ bv,
                  const float* __restrict__ bo, float* __restrict__ bvo)
{
    const int j = blockIdx.x, t = threadIdx.x;
    __shared__ float ws4[4];
    const float* wr = Wo + (size_t)j * 1024;
    float s = 0.0f;
#pragma unroll
    for (int i = 0; i < 4; ++i) s += wr[t + i * 256] * bv[t + i * 256];
#pragma unroll
    for (int o = 32; o > 0; o >>= 1) s += __shfl_down(s, o);
    if ((t & 63) == 0) ws4[t >> 6] = s;
    __syncthreads();
    if (t == 0) bvo[j] = ws4[0] + ws4[1] + ws4[2] + ws4[3] + bo[j];
}

__global__ __launch_bounds__(256)
void cast_act(const float* __restrict__ src, bf16_t* __restrict__ dst)
{
    const size_t i = ((size_t)blockIdx.x * 256 + threadIdx.x) * 4;
    const float4 f = *(const float4*)(src + i);
    bf16x4 h = {(bf16_t)f.x, (bf16_t)f.y, (bf16_t)f.z, (bf16_t)f.w};
    *(bf16x4*)(dst + i) = h;
}

__global__ __launch_bounds__(256)
void concat_bias(const float* __restrict__ a, const float* __restrict__ b,
                 float* __restrict__ dst)
{
    const int i = blockIdx.x * 256 + threadIdx.x;
    if (i < 1024) dst[i] = a[i];
    else if (i < 2048) dst[i] = b[i - 1024];
}

// ---------------------------------------------------------------------------
// One block per row: dual l2norm + sigmoid gate + exact top-80 (radix select
// on abs bits, stable lowest-index tie-break) + sparse write + visual concat.
// Scans are wave-level shfl_up (2 barriers/pass instead of 16).
// ---------------------------------------------------------------------------
__global__ __launch_bounds__(256)
void finalize_topk(float* __restrict__ AgF,      // OUT2: in Ag, out final
                   float* __restrict__ AlF,      // OUT3: in Al, out f2
                   const float* __restrict__ VIS,
                   float* __restrict__ O1)
{
    const int row = blockIdx.x, t = threadIdx.x;
    __shared__ int bins[256];
    __shared__ float wred[8];
    __shared__ int wsum[4];
    __shared__ int s_sel, s_kk;

    float* agp = AgF + (size_t)row * 1024 + t * 4;
    float* alp = AlF + (size_t)row * 1024 + t * 4;
    const float4 a4 = *(const float4*)agp;
    const float4 l4 = *(const float4*)alp;
    float av[4] = {a4.x, a4.y, a4.z, a4.w};
    float lv[4] = {l4.x, l4.y, l4.z, l4.w};
    float sa = 0.0f, sb = 0.0f;
#pragma unroll
    for (int j = 0; j < 4; ++j) { sa += av[j] * av[j]; sb += lv[j] * lv[j]; }
#pragma unroll
    for (int o = 32; o > 0; o >>= 1) {
        sa += __shfl_down(sa, o);
        sb += __shfl_down(sb, o);
    }
    if ((t & 63) == 0) { wred[t >> 6] = sa; wred[4 + (t >> 6)] = sb; }
    __syncthreads();
    const float sca = 1.0f / fmaxf(sqrtf(wred[0] + wred[1] + wred[2] + wred[3]), 1e-12f);
    const float scl = 1.0f / fmaxf(sqrtf(wred[4] + wred[5] + wred[6] + wred[7]), 1e-12f);

    float fv[4], f2v[4];
    unsigned ab[4];
#pragma unroll
    for (int j = 0; j < 4; ++j) {
        const float f2 = lv[j] * scl;
        const float f1 = av[j] * sca;
        const float fin = f2 / (1.0f + __expf(-f1));   // sigmoid(f1)*f2
        f2v[j] = f2; fv[j] = fin;
        ab[j] = __float_as_uint(fin) & 0x7fffffffu;
    }
    *(float4*)alp = make_float4(f2v[0], f2v[1], f2v[2], f2v[3]);
    *(float4*)agp = make_float4(fv[0], fv[1], fv[2], fv[3]);

    const float* vr = VIS + (size_t)row * 2048;
    float* o1r = O1 + (size_t)row * 3072;
    *(float4*)(o1r + t * 4)        = *(const float4*)(vr + t * 4);
    *(float4*)(o1r + 1024 + t * 4) = *(const float4*)(vr + 1024 + t * 4);

    // --- radix select: exact bits of the 80th-largest |fin| ---
    unsigned pref = 0u, msk = 0u;
    int kk = 80;
    for (int bp = 3; bp >= 0; --bp) {
        bins[t] = 0;
        __syncthreads();
#pragma unroll
        for (int j = 0; j < 4; ++j)
            if ((ab[j] & msk) == pref)
                atomicAdd(&bins[(ab[j] >> (bp * 8)) & 255], 1);
        __syncthreads();
        const int x = bins[t];
        int p = x;
#pragma unroll
        for (int o = 1; o < 64; o <<= 1) {
            const int y = __shfl_up(p, o);
            if ((t & 63) >= o) p += y;
        }
        if ((t & 63) == 63) wsum[t >> 6] = p;
        __syncthreads();
        const int tot = wsum[0] + wsum[1] + wsum[2] + wsum[3];
        int off = 0;
        if ((t >> 6) > 0) off += wsum[0];
        if ((t >> 6) > 1) off += wsum[1];
        if ((t >> 6) > 2) off += wsum[2];
        p += off;                              // inclusive prefix over 256
        const int Sme = tot - p + x;           // suffix sum incl. bin t
        const int Snx = tot - p;               // suffix sum from bin t+1
        if (Sme >= kk && Snx < kk) { s_sel = t; s_kk = kk - Snx; }
        __syncthreads();
        pref |= (unsigned)s_sel << (bp * 8);
        msk  |= 0xFFu << (bp * 8);
        kk = s_kk;
        __syncthreads();
    }

    // stable tie-break: keep first kk elements equal to threshold (index order)
    int ec = 0;
#pragma unroll
    for (int j = 0; j < 4; ++j) ec += (ab[j] == pref) ? 1 : 0;
    int pe = ec;
#pragma unroll
    for (int o = 1; o < 64; o <<= 1) {
        const int y = __shfl_up(pe, o);
        if ((t & 63) >= o) pe += y;
    }
    if ((t & 63) == 63) wsum[t >> 6] = pe;
    __syncthreads();
    int off2 = 0;
    if ((t >> 6) > 0) off2 += wsum[0];
    if ((t >> 6) > 1) off2 += wsum[1];
    if ((t >> 6) > 2) off2 += wsum[2];
    int excl = pe + off2 - ec;
#pragma unroll
    for (int j = 0; j < 4; ++j) {
        const bool eq = (ab[j] == pref);
        const bool kp = (ab[j] > pref) || (eq && (excl < kk));
        o1r[2048 + t * 4 + j] = kp ? fv[j] : 0.0f;
        if (eq) ++excl;
    }
}

// ---------------------------------------------------------------------------
extern "C" void kernel_launch(void* const* d_in, const int* in_sizes, int n_in,
                              void* d_out, int out_size, void* d_ws, size_t ws_size,
                              hipStream_t stream)
{
    const float* SG   = (const float*)d_in[0];
    const float* SL   = (const float*)d_in[1];
    const float* VIS  = (const float*)d_in[2];
    const float* Wgu1 = (const float*)d_in[3];
    const float* bgu1 = (const float*)d_in[4];
    const float* Wgu2 = (const float*)d_in[5];  const float* bgu2 = (const float*)d_in[6];
    const float* Wgd1 = (const float*)d_in[7];  const float* bgd1 = (const float*)d_in[8];
    const float* Wgd2 = (const float*)d_in[9];  const float* bgd2 = (const float*)d_in[10];
    const float* Wlu1 = (const float*)d_in[11]; const float* blu1 = (const float*)d_in[12];
    const float* Wlu2 = (const float*)d_in[13]; const float* blu2 = (const float*)d_in[14];
    const float* Wld1 = (const float*)d_in[15]; const float* bld1 = (const float*)d_in[16];
    const float* Wld2 = (const float*)d_in[17]; const float* bld2 = (const float*)d_in[18];
    const float* Wo   = (const float*)d_in[19]; const float* bo   = (const float*)d_in[20];
    const float* Win  = (const float*)d_in[21]; const float* bin_ = (const float*)d_in[22];
    const float* Wv = Win + (size_t)2 * 1024 * 1024;   // Win[2E:]
    const float* bv = bin_ + 2048;

    float* OUT1 = (float*)d_out;                         // B x 3072
    float* OUT2 = OUT1 + (size_t)16384 * 3072;           // B x 1024 (final)
    float* OUT3 = OUT2 + (size_t)16384 * 1024;           // B x 1024 (f2)

    // ws: bf16 weights (8 MLP + Wo + composed Wvo) + biases  (~21 MB)
    char* ws = (char*)d_ws;
    bf16_t* Wbf  = (bf16_t*)ws;                          // 8 x 1M (MLP)
    bf16_t* Wo_b = Wbf + (size_t)8 * 1048576;            // [16,18) MB
    bf16_t* Wvo  = Wbf + (size_t)9 * 1048576;            // [18,20) MB
    float*  bb   = (float*)(ws + 20971520);              // 4096 f32
    float*  bvo  = bb + 4096;                            // 1024 f32

    // scratch inside d_out (320 MiB), lifetime-checked (see r2/r5 notes)
    bf16_t* X   = (bf16_t*)d_out;
    bf16_t* Y   = X + (size_t)16384 * 1024;
    bf16_t* Ug  = (bf16_t*)((char*)d_out + 67108864);
    bf16_t* Ul  = (bf16_t*)((char*)d_out + 100663296);
    bf16_t* H1g = (bf16_t*)((char*)d_out + 134217728);
    bf16_t* H1l = (bf16_t*)((char*)d_out + 201326592);
    bf16_t* WvT = H1g;                                   // transient, pre-D1

    WSrcs srcs;
    srcs.p[0] = Wgu1; srcs.p[1] = Wgd1; srcs.p[2] = Wlu1; srcs.p[3] = Wld1;
    srcs.p[4] = Wgu2; srcs.p[5] = Wgd2; srcs.p[6] = Wlu2; srcs.p[7] = Wld2;
    srcs.p[8] = Wo;

    cast_weights<<<9216, 256, 0, stream>>>(srcs, Wbf);
    transpose_cast<<<dim3(16, 16), 256, 0, stream>>>(Wv, WvT);
    concat_bias<<<8, 256, 0, stream>>>(bgu1, bgd1, bb);
    concat_bias<<<8, 256, 0, stream>>>(blu1, bld1, bb + 2048);
    bias_compose<<<1024, 256, 0, stream>>>(Wo, bv, bo, bvo);
    cast_act<<<16384, 256, 0, stream>>>(SG, X);
    cast_act<<<16384, 256, 0, stream>>>(SL, Y);

    // Wvo[n][k] = sum_m Wo[n][m] * Wv[m][k]  (= Wo @ Wv), bf16
    gemm_small_bt<<<dim3(8, 8), 256, 0, stream>>>(Wo_b, 1024, WvT, Wvo, 1024, 1024);

    bf16_t* Wg1   = Wbf;                                 // [Wgu1;Wgd1] 2048x1024
    bf16_t* Wl1   = Wbf + (size_t)2 * 1048576;           // [Wlu1;Wld1]
    bf16_t* Wgu2b = Wbf + (size_t)4 * 1048576;
    bf16_t* Wgd2b = Wbf + (size_t)5 * 1048576;
    bf16_t* Wlu2b = Wbf + (size_t)6 * 1048576;
    bf16_t* Wld2b = Wbf + (size_t)7 * 1048576;

    // D1: h1 = relu([X;Y] @ [W?u1;W?d1]^T + b), per-half weights. N=2048.
    gemm128<0><<<4096, 256, 0, stream>>>(X, Y, 1024, Wg1, Wl1, bb, bb + 2048,
                                         nullptr, nullptr, H1g, H1l, 2048, 1024, 16, 128, 32);
    // D2: U = h1[:, :1024] @ W?u2^T + b  (gate pre-act)
    gemm128<1><<<2048, 256, 0, stream>>>(H1g, H1l, 2048, Wgu2b, Wlu2b, bgu2, blu2,
                                         nullptr, nullptr, Ug, Ul, 1024, 1024, 8, 128, 16);
    // D3: s? = sigmoid(U) * (h1[:, 1024:] @ W?d2^T + b)  -> X, Y
    gemm128<2><<<2048, 256, 0, stream>>>(H1g + 1024, H1l + 1024, 2048, Wgd2b, Wld2b,
                                         bgd2, bld2, Ug, Ul, X, Y, 1024, 1024, 8, 128, 16);
    // D45: pre-norm attn_out = [sg;sl] @ Wvo^T + bvo -> OUT2/OUT3 (M=32768)
    gemm128<3><<<2048, 256, 0, stream>>>(X, X, 1024, Wvo, Wvo, bvo, bvo,
                                         nullptr, nullptr, OUT2, OUT2, 1024, 1024, 8, 256, 8);

    finalize_topk<<<16384, 256, 0, stream>>>(OUT2, OUT3, VIS, OUT1);
}

// Round 9
// 440.757 us; speedup vs baseline: 1.4609x; 1.3533x over previous
//
#include <hip/hip_runtime.h>

typedef __bf16 bf16_t;
typedef __bf16 bf16x4 __attribute__((ext_vector_type(4)));
typedef __bf16 bf16x8 __attribute__((ext_vector_type(8)));
typedef float f32x4 __attribute__((ext_vector_type(4)));
typedef int i32x4v __attribute__((ext_vector_type(4)));
typedef int i32x8v __attribute__((ext_vector_type(8)));

#define GLL16(gp, lp) __builtin_amdgcn_global_load_lds( \
    (__attribute__((address_space(1))) void*)(gp),      \
    (__attribute__((address_space(3))) void*)(lp), 16, 0, 0)

__device__ inline unsigned char f32_to_fp8(float v)
{
    return (unsigned char)(__builtin_amdgcn_cvt_pk_fp8_f32(v, v, 0, false) & 0xff);
}

__device__ inline i32x8v join8(i32x4v a, i32x4v b)
{
    i32x8v r;
    r[0] = a[0]; r[1] = a[1]; r[2] = a[2]; r[3] = a[3];
    r[4] = b[0]; r[5] = b[1]; r[6] = b[2]; r[7] = b[3];
    return r;
}

// ---------------------------------------------------------------------------
// 128x128-tile MX-fp8 GEMM, m97 structure (r8-verified skeleton), BK=128.
//   C[half][M,N] = epi(A[half][M,K] @ W[half][N,K]^T + bias[half])
// 256 threads (4 waves 2x2); 32 KiB LDS single-buffered; 2 barriers/K-tile;
// multiple blocks/CU give the cross-block overlap (m97/m114 mechanism).
// MFMA: mfma_scale_f32_16x16x128_f8f6f4, A-fmt=B-fmt=fp8(e4m3).
// UNIFORM scales (lane-mapping-immune): A-scale 2^0 (0x7F); weights stored
// as fp8(16*W) with B-scale 2^-4 (0x7B) -> escapes e4m3 subnormal zone.
// Fragment: lane l holds row l&15, k-bytes [32*(l>>4), +32) = 2x ds_read_b128.
// Swizzle: 16B-granule (8/row) XOR by row&7 on BOTH staging source and
// ds_read (involution) -> quarter-wave 2 lanes/bank = conflict-free.
// Epilogue n-innermost. XCD windows: 8-byh x 4-c per window.
// EPI: 0 relu->fp8, 1 bias->bf16, 2 sigmoid(U)*v->fp8, 3 bias->f32
// ---------------------------------------------------------------------------
template<int EPI>
__global__ __launch_bounds__(256, 3)
void gemm128_f8(const unsigned char* __restrict__ A0,
                const unsigned char* __restrict__ A1, int lda,
                const unsigned char* __restrict__ W0,
                const unsigned char* __restrict__ W1,
                const float* __restrict__ bias0, const float* __restrict__ bias1,
                const bf16_t* __restrict__ U0, const bf16_t* __restrict__ U1,
                void* __restrict__ C0v, void* __restrict__ C1v, int ldc,
                int K, int nbx, int nbyH, int ctot)
{
    __shared__ __attribute__((aligned(64))) unsigned char As[128 * 128];
    __shared__ __attribute__((aligned(64))) unsigned char Bs[128 * 128];

    const int t = threadIdx.x;
    const int w = t >> 6, l = t & 63;
    const int wr = w >> 1, wc = w & 1;        // 2 x 2 wave grid
    const int ro = l & 15, hi = l >> 4;
    const int sw = ro & 7;                    // = row&7 for all frag rows
    const int gA = (((hi << 1) ^ sw) * 16);   // first 16B granule byte offset

    // XCD-window remap (gridDim%8==0, nbyH%8==0, ctot%4==0)
    const int xcd   = blockIdx.x & 7;
    const int local = blockIdx.x >> 3;
    const int wpb   = ctot >> 2;
    const int win   = local >> 5;
    const int r5    = local & 31;
    const int strp  = win / wpb;
    const int wcn   = win - strp * wpb;
    const int byh   = xcd * (nbyH >> 3) + strp * 8 + (r5 >> 2);
    const int c     = wcn * 4 + (r5 & 3);
    const int sel   = (c >= nbx) ? 1 : 0;
    const int bx    = c - sel * nbx;

    const unsigned char* A    = sel ? A1 : A0;
    const unsigned char* W    = sel ? W1 : W0;
    const float*  bias = sel ? bias1 : bias0;
    const bf16_t* Up   = sel ? U1 : U0;
    void*         Cp   = sel ? C1v : C0v;

    const unsigned char* Ab = A + (size_t)byh * 128 * lda;
    const unsigned char* Wb = W + (size_t)bx * 128 * K;

    // pre-swizzled staging sources: granule g -> row g>>3, src col-granule
    // (g&7)^(row&7); LDS dst is linear (wave-uniform base + lane*16).
    const unsigned char* asrc[4];
    const unsigned char* bsrc[4];
#pragma unroll
    for (int r = 0; r < 4; ++r) {
        const int g   = r * 256 + t;          // 1024 granules per 128x128B tile
        const int row = g >> 3;
        const int cg  = (g & 7) ^ (row & 7);
        asrc[r] = Ab + (size_t)row * lda + cg * 16;
        bsrc[r] = Wb + (size_t)row * K   + cg * 16;
    }

    f32x4 acc[4][4] = {};

    for (int kt = 0; kt < K; kt += 128) {
#pragma unroll
        for (int r = 0; r < 4; ++r) {
            GLL16(asrc[r], &As[(r * 256 + w * 64) * 16]);
            GLL16(bsrc[r], &Bs[(r * 256 + w * 64) * 16]);
            asrc[r] += 128;
            bsrc[r] += 128;
        }
        __syncthreads();
        i32x8v bq[4];
#pragma unroll
        for (int n = 0; n < 4; ++n) {
            const unsigned char* bp = Bs + (wc * 64 + n * 16 + ro) * 128;
            bq[n] = join8(*(const i32x4v*)(bp + gA),
                          *(const i32x4v*)(bp + (gA ^ 16)));
        }
#pragma unroll
        for (int m = 0; m < 4; ++m) {
            const unsigned char* ap = As + (wr * 64 + m * 16 + ro) * 128;
            const i32x8v af = join8(*(const i32x4v*)(ap + gA),
                                    *(const i32x4v*)(ap + (gA ^ 16)));
#pragma unroll
            for (int n = 0; n < 4; ++n)
                acc[m][n] = __builtin_amdgcn_mfma_scale_f32_16x16x128_f8f6f4(
                    af, bq[n], acc[m][n], 0, 0,
                    0, 0x7F7F7F7F,      // A scale = 2^0 (uniform)
                    0, 0x7B7B7B7B);     // B scale = 2^-4 (weights stored x16)
        }
        __syncthreads();
    }

    // epilogue: C/D frag layout col=lane&15, row=(lane>>4)*4+j  [guide m89]
    const int rbase = byh * 128 + wr * 64 + (hi << 2);
    const int cbase = bx * 128 + wc * 64 + ro;
    float bc[4];
#pragma unroll
    for (int n = 0; n < 4; ++n) bc[n] = bias[cbase + n * 16];
#pragma unroll
    for (int m = 0; m < 4; ++m) {
#pragma unroll
        for (int j = 0; j < 4; ++j) {
            const int row = rbase + m * 16 + j;
            const size_t off = (size_t)row * ldc + cbase;
#pragma unroll
            for (int n = 0; n < 4; ++n) {
                float v = acc[m][n][j] + bc[n];
                if (EPI == 0) v = fmaxf(v, 0.0f);
                if (EPI == 2) {
                    const float u = (float)Up[off + n * 16];
                    v *= 1.0f / (1.0f + __expf(-u));
                }
                if (EPI == 3)      ((float*)Cp)[off + n * 16] = v;
                else if (EPI == 1) ((bf16_t*)Cp)[off + n * 16] = (bf16_t)v;
                else ((unsigned char*)Cp)[off + n * 16] = f32_to_fp8(v);
            }
        }
    }
}

// ---------------------------------------------------------------------------
// Small bf16 128x128-tile GEMM for the Wo@Wv compose; writes fp8(16*C).
// ---------------------------------------------------------------------------
__global__ __launch_bounds__(256, 2)
void gemm_small_bt(const bf16_t* __restrict__ A, int lda,
                   const bf16_t* __restrict__ W,
                   unsigned char* __restrict__ C, int ldc, int K)
{
    __shared__ bf16_t As[128 * 64];
    __shared__ bf16_t Bs[128 * 64];
    const int t = threadIdx.x;
    const int w = t >> 6, l = t & 63;
    const int wr = w >> 1, wc = w & 1;

    const bf16_t* Ab = A + (size_t)blockIdx.y * 128 * lda;
    const bf16_t* Wb = W + (size_t)blockIdx.x * 128 * K;

    const bf16_t* asrc[4];
    const bf16_t* bsrc[4];
#pragma unroll
    for (int r = 0; r < 4; ++r) {
        const int seg = r * 256 + t;
        asrc[r] = Ab + (size_t)(seg >> 3) * lda + (seg & 7) * 8;
        bsrc[r] = Wb + (size_t)(seg >> 3) * K   + (seg & 7) * 8;
    }

    f32x4 acc[4][4] = {};

    for (int kt = 0; kt < K; kt += 64) {
#pragma unroll
        for (int r = 0; r < 4; ++r) {
            GLL16(asrc[r], As + (r * 256 + w * 64) * 8);
            GLL16(bsrc[r], Bs + (r * 256 + w * 64) * 8);
            asrc[r] += 64;
            bsrc[r] += 64;
        }
        __syncthreads();
#pragma unroll
        for (int kk = 0; kk < 2; ++kk) {
            const int ro = l & 15;
            const int ko = kk * 32 + (l >> 4) * 8;
            bf16x8 af[4], bqv[4];
#pragma unroll
            for (int m = 0; m < 4; ++m)
                af[m] = *(const bf16x8*)(As + (wr * 64 + m * 16 + ro) * 64 + ko);
#pragma unroll
            for (int n = 0; n < 4; ++n)
                bqv[n] = *(const bf16x8*)(Bs + (wc * 64 + n * 16 + ro) * 64 + ko);
#pragma unroll
            for (int m = 0; m < 4; ++m)
#pragma unroll
                for (int n = 0; n < 4; ++n)
                    acc[m][n] = __builtin_amdgcn_mfma_f32_16x16x32_bf16(
                        af[m], bqv[n], acc[m][n], 0, 0, 0);
        }
        __syncthreads();
    }

    const int rbase = blockIdx.y * 128 + wr * 64 + ((l >> 4) << 2);
    const int cbase = blockIdx.x * 128 + wc * 64 + (l & 15);
#pragma unroll
    for (int m = 0; m < 4; ++m)
#pragma unroll
        for (int j = 0; j < 4; ++j) {
            const int row = rbase + m * 16 + j;
#pragma unroll
            for (int n = 0; n < 4; ++n)
                C[(size_t)row * ldc + cbase + n * 16] =
                    f32_to_fp8(acc[m][n][j] * 16.0f);
        }
}

// ---------------------------------------------------------------------------
struct W8Srcs { const float* p[8]; };

// 8 MLP weight matrices f32 -> fp8(16*w). 512 blocks per 1M-element region.
__global__ __launch_bounds__(256)
void cast_w8(W8Srcs srcs, unsigned char* __restrict__ dst)
{
    const int region = blockIdx.x >> 9;
    const float* src = srcs.p[region];
    const size_t base = (size_t)(blockIdx.x & 511) * 2048 + threadIdx.x * 8;
    const float4 f0 = *(const float4*)(src + base);
    const float4 f1 = *(const float4*)(src + base + 4);
    int a = __builtin_amdgcn_cvt_pk_fp8_f32(f0.x * 16.f, f0.y * 16.f, 0, false);
    a     = __builtin_amdgcn_cvt_pk_fp8_f32(f0.z * 16.f, f0.w * 16.f, a, true);
    int b = __builtin_amdgcn_cvt_pk_fp8_f32(f1.x * 16.f, f1.y * 16.f, 0, false);
    b     = __builtin_amdgcn_cvt_pk_fp8_f32(f1.z * 16.f, f1.w * 16.f, b, true);
    *(int2*)(dst + ((size_t)region << 20) + base) = make_int2(a, b);
}

// f32 -> fp8 (x1), 8 elems/thread
__global__ __launch_bounds__(256)
void cast_act_f8(const float* __restrict__ src, unsigned char* __restrict__ dst)
{
    const size_t i = ((size_t)blockIdx.x * 256 + threadIdx.x) * 8;
    const float4 f0 = *(const float4*)(src + i);
    const float4 f1 = *(const float4*)(src + i + 4);
    int a = __builtin_amdgcn_cvt_pk_fp8_f32(f0.x, f0.y, 0, false);
    a     = __builtin_amdgcn_cvt_pk_fp8_f32(f0.z, f0.w, a, true);
    int b = __builtin_amdgcn_cvt_pk_fp8_f32(f1.x, f1.y, 0, false);
    b     = __builtin_amdgcn_cvt_pk_fp8_f32(f1.z, f1.w, b, true);
    *(int2*)(dst + i) = make_int2(a, b);
}

// f32 -> bf16, 4 elems/thread (used for Wo)
__global__ __launch_bounds__(256)
void cast_act(const float* __restrict__ src, bf16_t* __restrict__ dst)
{
    const size_t i = ((size_t)blockIdx.x * 256 + threadIdx.x) * 4;
    const float4 f = *(const float4*)(src + i);
    bf16x4 h = {(bf16_t)f.x, (bf16_t)f.y, (bf16_t)f.z, (bf16_t)f.w};
    *(bf16x4*)(dst + i) = h;
}

// Wv[m][k] (f32) -> WvT[k][m] (bf16); 64x64 tiles via padded LDS.
__global__ __launch_bounds__(256)
void transpose_cast(const float* __restrict__ src, bf16_t* __restrict__ dst)
{
    __shared__ bf16_t tile[64][65];
    const int bm = blockIdx.y * 64, bk = blockIdx.x * 64;
    const int t = threadIdx.x;
#pragma unroll
    for (int s = 0; s < 4; ++s) {
        const int r = s * 16 + (t >> 4);
        const int c = (t & 15) * 4;
        const float4 f = *(const float4*)(src + (size_t)(bm + r) * 1024 + bk + c);
        tile[r][c] = (bf16_t)f.x; tile[r][c + 1] = (bf16_t)f.y;
        tile[r][c + 2] = (bf16_t)f.z; tile[r][c + 3] = (bf16_t)f.w;
    }
    __syncthreads();
#pragma unroll
    for (int s = 0; s < 4; ++s) {
        const int k = s * 16 + (t >> 4);
        const int m = (t & 15) * 4;
        bf16x4 v = {tile[m][k], tile[m + 1][k], tile[m + 2][k], tile[m + 3][k]};
        *(bf16x4*)(dst + (size_t)(bk + k) * 1024 + bm + m) = v;
    }
}

// bvo[j] = dot(Wo[j,:], bv) + bo[j]
__global__ __launch_bounds__(256)
void bias_compose(const float* __restrict__ Wo, const float* __restrict__ bv,
                  const float* __restrict__ bo, float* __restrict__ bvo)
{
    const int j = blockIdx.x, t = threadIdx.x;
    __shared__ float ws4[4];
    const float* wr = Wo + (size_t)j * 1024;
    float s = 0.0f;
#pragma unroll
    for (int i = 0; i < 4; ++i) s += wr[t + i * 256] * bv[t + i * 256];
#pragma unroll
    for (int o = 32; o > 0; o >>= 1) s += __shfl_down(s, o);
    if ((t & 63) == 0) ws4[t >> 6] = s;
    __syncthreads();
    if (t == 0) bvo[j] = ws4[0] + ws4[1] + ws4[2] + ws4[3] + bo[j];
}

__global__ __launch_bounds__(256)
void concat_bias(const float* __restrict__ a, const float* __restrict__ b,
                 float* __restrict__ dst)
{
    const int i = blockIdx.x * 256 + threadIdx.x;
    if (i < 1024) dst[i] = a[i];
    else if (i < 2048) dst[i] = b[i - 1024];
}

// ---------------------------------------------------------------------------
// One block per row: dual l2norm + sigmoid gate + exact top-80 (radix select
// on abs bits, stable lowest-index tie-break) + sparse write + visual concat.
// ---------------------------------------------------------------------------
__global__ __launch_bounds__(256)
void finalize_topk(float* __restrict__ AgF,      // OUT2: in Ag, out final
                   float* __restrict__ AlF,      // OUT3: in Al, out f2
                   const float* __restrict__ VIS,
                   float* __restrict__ O1)
{
    const int row = blockIdx.x, t = threadIdx.x;
    __shared__ int bins[256];
    __shared__ float wred[8];
    __shared__ int wsum[4];
    __shared__ int s_sel, s_kk;

    float* agp = AgF + (size_t)row * 1024 + t * 4;
    float* alp = AlF + (size_t)row * 1024 + t * 4;
    const float4 a4 = *(const float4*)agp;
    const float4 l4 = *(const float4*)alp;
    float av[4] = {a4.x, a4.y, a4.z, a4.w};
    float lv[4] = {l4.x, l4.y, l4.z, l4.w};
    float sa = 0.0f, sb = 0.0f;
#pragma unroll
    for (int j = 0; j < 4; ++j) { sa += av[j] * av[j]; sb += lv[j] * lv[j]; }
#pragma unroll
    for (int o = 32; o > 0; o >>= 1) {
        sa += __shfl_down(sa, o);
        sb += __shfl_down(sb, o);
    }
    if ((t & 63) == 0) { wred[t >> 6] = sa; wred[4 + (t >> 6)] = sb; }
    __syncthreads();
    const float sca = 1.0f / fmaxf(sqrtf(wred[0] + wred[1] + wred[2] + wred[3]), 1e-12f);
    const float scl = 1.0f / fmaxf(sqrtf(wred[4] + wred[5] + wred[6] + wred[7]), 1e-12f);

    float fv[4], f2v[4];
    unsigned ab[4];
#pragma unroll
    for (int j = 0; j < 4; ++j) {
        const float f2 = lv[j] * scl;
        const float f1 = av[j] * sca;
        const float fin = f2 / (1.0f + __expf(-f1));   // sigmoid(f1)*f2
        f2v[j] = f2; fv[j] = fin;
        ab[j] = __float_as_uint(fin) & 0x7fffffffu;
    }
    *(float4*)alp = make_float4(f2v[0], f2v[1], f2v[2], f2v[3]);
    *(float4*)agp = make_float4(fv[0], fv[1], fv[2], fv[3]);

    const float* vr = VIS + (size_t)row * 2048;
    float* o1r = O1 + (size_t)row * 3072;
    *(float4*)(o1r + t * 4)        = *(const float4*)(vr + t * 4);
    *(float4*)(o1r + 1024 + t * 4) = *(const float4*)(vr + 1024 + t * 4);

    // --- radix select: exact bits of the 80th-largest |fin| ---
    unsigned pref = 0u, msk = 0u;
    int kk = 80;
    for (int bp = 3; bp >= 0; --bp) {
        bins[t] = 0;
        __syncthreads();
#pragma unroll
        for (int j = 0; j < 4; ++j)
            if ((ab[j] & msk) == pref)
                atomicAdd(&bins[(ab[j] >> (bp * 8)) & 255], 1);
        __syncthreads();
        const int x = bins[t];
        int p = x;
#pragma unroll
        for (int o = 1; o < 64; o <<= 1) {
            const int y = __shfl_up(p, o);
            if ((t & 63) >= o) p += y;
        }
        if ((t & 63) == 63) wsum[t >> 6] = p;
        __syncthreads();
        const int tot = wsum[0] + wsum[1] + wsum[2] + wsum[3];
        int off = 0;
        if ((t >> 6) > 0) off += wsum[0];
        if ((t >> 6) > 1) off += wsum[1];
        if ((t >> 6) > 2) off += wsum[2];
        p += off;                              // inclusive prefix over 256
        const int Sme = tot - p + x;           // suffix sum incl. bin t
        const int Snx = tot - p;               // suffix sum from bin t+1
        if (Sme >= kk && Snx < kk) { s_sel = t; s_kk = kk - Snx; }
        __syncthreads();
        pref |= (unsigned)s_sel << (bp * 8);
        msk  |= 0xFFu << (bp * 8);
        kk = s_kk;
        __syncthreads();
    }

    // stable tie-break: keep first kk elements equal to threshold (index order)
    int ec = 0;
#pragma unroll
    for (int j = 0; j < 4; ++j) ec += (ab[j] == pref) ? 1 : 0;
    int pe = ec;
#pragma unroll
    for (int o = 1; o < 64; o <<= 1) {
        const int y = __shfl_up(pe, o);
        if ((t & 63) >= o) pe += y;
    }
    if ((t & 63) == 63) wsum[t >> 6] = pe;
    __syncthreads();
    int off2 = 0;
    if ((t >> 6) > 0) off2 += wsum[0];
    if ((t >> 6) > 1) off2 += wsum[1];
    if ((t >> 6) > 2) off2 += wsum[2];
    int excl = pe + off2 - ec;
#pragma unroll
    for (int j = 0; j < 4; ++j) {
        const bool eq = (ab[j] == pref);
        const bool kp = (ab[j] > pref) || (eq && (excl < kk));
        o1r[2048 + t * 4 + j] = kp ? fv[j] : 0.0f;
        if (eq) ++excl;
    }
}

// ---------------------------------------------------------------------------
extern "C" void kernel_launch(void* const* d_in, const int* in_sizes, int n_in,
                              void* d_out, int out_size, void* d_ws, size_t ws_size,
                              hipStream_t stream)
{
    const float* SG   = (const float*)d_in[0];
    const float* SL   = (const float*)d_in[1];
    const float* VIS  = (const float*)d_in[2];
    const float* Wgu1 = (const float*)d_in[3];
    const float* bgu1 = (const float*)d_in[4];
    const float* Wgu2 = (const float*)d_in[5];  const float* bgu2 = (const float*)d_in[6];
    const float* Wgd1 = (const float*)d_in[7];  const float* bgd1 = (const float*)d_in[8];
    const float* Wgd2 = (const float*)d_in[9];  const float* bgd2 = (const float*)d_in[10];
    const float* Wlu1 = (const float*)d_in[11]; const float* blu1 = (const float*)d_in[12];
    const float* Wlu2 = (const float*)d_in[13]; const float* blu2 = (const float*)d_in[14];
    const float* Wld1 = (const float*)d_in[15]; const float* bld1 = (const float*)d_in[16];
    const float* Wld2 = (const float*)d_in[17]; const float* bld2 = (const float*)d_in[18];
    const float* Wo   = (const float*)d_in[19]; const float* bo   = (const float*)d_in[20];
    const float* Win  = (const float*)d_in[21]; const float* bin_ = (const float*)d_in[22];
    const float* Wv = Win + (size_t)2 * 1024 * 1024;   // Win[2E:]
    const float* bv = bin_ + 2048;

    float* OUT1 = (float*)d_out;                         // B x 3072
    float* OUT2 = OUT1 + (size_t)16384 * 3072;           // B x 1024 (final)
    float* OUT3 = OUT2 + (size_t)16384 * 1024;           // B x 1024 (f2)

    // ws: fp8 weights (8 MLP, x16) + bf16 Wo + fp8 Wvo(x16) + biases (~12 MB)
    char* ws = (char*)d_ws;
    unsigned char* Wf8 = (unsigned char*)ws;             // [0, 8M)
    bf16_t* Wo_b = (bf16_t*)(ws + (8u << 20));           // [8M, 10M)
    unsigned char* Wvo = (unsigned char*)(ws + (10u << 20)); // [10M, 11M)
    float* bb  = (float*)(ws + (11u << 20));             // 4096 f32
    float* bvo = bb + 4096;                              // 1024 f32

    // scratch inside d_out (320 MiB), lifetime-checked:
    //   X [0,16)M  Y [16,32)M : fp8 sg/sl, rewritten by D3 as sg'/sl'
    //   Ug [64,96)M  Ul [96,128)M : bf16 gate pre-acts (D2 out, D3 in)
    //   H1g [128,160)M  H1l [160,192)M : fp8 hidden (D1 out, dead after D3)
    //   WvT (2MB, bf16) transient in H1g slot pre-D1.
    //   D45 writes OUT2/OUT3 [192,320)M; finalize overwrites [0,192)M (OUT1).
    unsigned char* X   = (unsigned char*)d_out;
    unsigned char* Y   = X + (16u << 20);
    bf16_t* Ug  = (bf16_t*)((char*)d_out + (64u << 20));
    bf16_t* Ul  = (bf16_t*)((char*)d_out + (96u << 20));
    unsigned char* H1g = (unsigned char*)d_out + (128u << 20);
    unsigned char* H1l = H1g + (32u << 20);
    bf16_t* WvT = (bf16_t*)H1g;                          // transient, pre-D1

    W8Srcs s8;
    s8.p[0] = Wgu1; s8.p[1] = Wgd1; s8.p[2] = Wlu1; s8.p[3] = Wld1;
    s8.p[4] = Wgu2; s8.p[5] = Wgd2; s8.p[6] = Wlu2; s8.p[7] = Wld2;

    cast_w8<<<4096, 256, 0, stream>>>(s8, Wf8);
    cast_act<<<1024, 256, 0, stream>>>(Wo, Wo_b);        // Wo -> bf16
    transpose_cast<<<dim3(16, 16), 256, 0, stream>>>(Wv, WvT);
    concat_bias<<<8, 256, 0, stream>>>(bgu1, bgd1, bb);
    concat_bias<<<8, 256, 0, stream>>>(blu1, bld1, bb + 2048);
    bias_compose<<<1024, 256, 0, stream>>>(Wo, bv, bo, bvo);
    cast_act_f8<<<8192, 256, 0, stream>>>(SG, X);
    cast_act_f8<<<8192, 256, 0, stream>>>(SL, Y);

    // Wvo = fp8(16 * Wo @ Wv)
    gemm_small_bt<<<dim3(8, 8), 256, 0, stream>>>(Wo_b, 1024, WvT, Wvo, 1024, 1024);

    unsigned char* Wg1   = Wf8;                          // [Wgu1;Wgd1] 2048x1024
    unsigned char* Wl1   = Wf8 + (size_t)2 * 1048576;    // [Wlu1;Wld1]
    unsigned char* Wgu2b = Wf8 + (size_t)4 * 1048576;
    unsigned char* Wgd2b = Wf8 + (size_t)5 * 1048576;
    unsigned char* Wlu2b = Wf8 + (size_t)6 * 1048576;
    unsigned char* Wld2b = Wf8 + (size_t)7 * 1048576;

    // D1: h1 = relu([X;Y] @ [W?u1;W?d1]^T + b) -> fp8. N=2048 per half.
    gemm128_f8<0><<<4096, 256, 0, stream>>>(X, Y, 1024, Wg1, Wl1, bb, bb + 2048,
                                            nullptr, nullptr, H1g, H1l, 2048, 1024, 16, 128, 32);
    // D2: U = h1[:, :1024] @ W?u2^T + b -> bf16 (gate pre-act)
    gemm128_f8<1><<<2048, 256, 0, stream>>>(H1g, H1l, 2048, Wgu2b, Wlu2b, bgu2, blu2,
                                            nullptr, nullptr, Ug, Ul, 1024, 1024, 8, 128, 16);
    // D3: s? = sigmoid(U) * (h1[:, 1024:] @ W?d2^T + b) -> fp8 into X, Y
    gemm128_f8<2><<<2048, 256, 0, stream>>>(H1g + 1024, H1l + 1024, 2048, Wgd2b, Wld2b,
                                            bgd2, bld2, Ug, Ul, X, Y, 1024, 1024, 8, 128, 16);
    // D45: pre-norm attn_out = [sg;sl] @ Wvo^T + bvo -> f32 OUT2/OUT3 (M=32768)
    gemm128_f8<3><<<2048, 256, 0, stream>>>(X, X, 1024, Wvo, Wvo, bvo, bvo,
                                            nullptr, nullptr, OUT2, OUT2, 1024, 1024, 8, 256, 8);

    finalize_topk<<<16384, 256, 0, stream>>>(OUT2, OUT3, VIS, OUT1);
}

// Round 10
// 403.874 us; speedup vs baseline: 1.5943x; 1.0913x over previous
//
#include <hip/hip_runtime.h>

typedef __bf16 bf16_t;
typedef __bf16 bf16x4 __attribute__((ext_vector_type(4)));
typedef __bf16 bf16x8 __attribute__((ext_vector_type(8)));
typedef float f32x4 __attribute__((ext_vector_type(4)));
typedef int i32x4v __attribute__((ext_vector_type(4)));
typedef int i32x8v __attribute__((ext_vector_type(8)));

#define GLL16(gp, lp) __builtin_amdgcn_global_load_lds( \
    (__attribute__((address_space(1))) void*)(gp),      \
    (__attribute__((address_space(3))) void*)(lp), 16, 0, 0)

__device__ inline unsigned char f32_to_fp8(float v)
{
    return (unsigned char)(__builtin_amdgcn_cvt_pk_fp8_f32(v, v, 0, false) & 0xff);
}

__device__ inline i32x8v join8(i32x4v a, i32x4v b)
{
    i32x8v r;
    r[0] = a[0]; r[1] = a[1]; r[2] = a[2]; r[3] = a[3];
    r[4] = b[0]; r[5] = b[1]; r[6] = b[2]; r[7] = b[3];
    return r;
}

// ---------------------------------------------------------------------------
// 128x128-tile MX-fp8 GEMM, m97 structure (r9-verified), BK=128.
//   C[half][M,N] = epi(A[half][M,K] @ W[half][N,K]^T + bias[half])
// 256 threads (4 waves 2x2); 32 KiB LDS single-buffered; 2 barriers/K-tile;
// multiple blocks/CU give cross-block overlap (m97/m114 mechanism).
// MFMA: mfma_scale_f32_16x16x128_f8f6f4, fp8 e4m3 both operands.
// UNIFORM scales: A 2^0 (0x7F); weights stored fp8(16*W), B-scale 2^-4 (0x7B).
// Swizzle: 16B-granule XOR row&7 both-sides. Epilogue n-innermost.
// XCD windows: 8-byh x 4-c.
// EPI: 0 relu->fp8, 1 bias->bf16, 2 sigmoid(U)*v->fp8, 3 bias->f32,
//      4 bias->bf16 interleaved into O1 rows (P layout: half h row r ->
//        (bf16*)O1 + r*6144 + h*1024; O1 row stride 3072 f32 = 6144 bf16)
// ---------------------------------------------------------------------------
template<int EPI>
__global__ __launch_bounds__(256, 3)
void gemm128_f8(const unsigned char* __restrict__ A0,
                const unsigned char* __restrict__ A1, int lda,
                const unsigned char* __restrict__ W0,
                const unsigned char* __restrict__ W1,
                const float* __restrict__ bias0, const float* __restrict__ bias1,
                const bf16_t* __restrict__ U0, const bf16_t* __restrict__ U1,
                void* __restrict__ C0v, void* __restrict__ C1v, int ldc,
                int K, int nbx, int nbyH, int ctot)
{
    __shared__ __attribute__((aligned(64))) unsigned char As[128 * 128];
    __shared__ __attribute__((aligned(64))) unsigned char Bs[128 * 128];

    const int t = threadIdx.x;
    const int w = t >> 6, l = t & 63;
    const int wr = w >> 1, wc = w & 1;        // 2 x 2 wave grid
    const int ro = l & 15, hi = l >> 4;
    const int sw = ro & 7;
    const int gA = (((hi << 1) ^ sw) * 16);   // first 16B granule byte offset

    // XCD-window remap (gridDim%8==0, nbyH%8==0, ctot%4==0)
    const int xcd   = blockIdx.x & 7;
    const int local = blockIdx.x >> 3;
    const int wpb   = ctot >> 2;
    const int win   = local >> 5;
    const int r5    = local & 31;
    const int strp  = win / wpb;
    const int wcn   = win - strp * wpb;
    const int byh   = xcd * (nbyH >> 3) + strp * 8 + (r5 >> 2);
    const int c     = wcn * 4 + (r5 & 3);
    const int sel   = (c >= nbx) ? 1 : 0;
    const int bx    = c - sel * nbx;

    const unsigned char* A    = sel ? A1 : A0;
    const unsigned char* W    = sel ? W1 : W0;
    const float*  bias = sel ? bias1 : bias0;
    const bf16_t* Up   = sel ? U1 : U0;
    void*         Cp   = sel ? C1v : C0v;

    const unsigned char* Ab = A + (size_t)byh * 128 * lda;
    const unsigned char* Wb = W + (size_t)bx * 128 * K;

    const unsigned char* asrc[4];
    const unsigned char* bsrc[4];
#pragma unroll
    for (int r = 0; r < 4; ++r) {
        const int g   = r * 256 + t;
        const int row = g >> 3;
        const int cg  = (g & 7) ^ (row & 7);
        asrc[r] = Ab + (size_t)row * lda + cg * 16;
        bsrc[r] = Wb + (size_t)row * K   + cg * 16;
    }

    f32x4 acc[4][4] = {};

    for (int kt = 0; kt < K; kt += 128) {
#pragma unroll
        for (int r = 0; r < 4; ++r) {
            GLL16(asrc[r], &As[(r * 256 + w * 64) * 16]);
            GLL16(bsrc[r], &Bs[(r * 256 + w * 64) * 16]);
            asrc[r] += 128;
            bsrc[r] += 128;
        }
        __syncthreads();
        i32x8v bq[4];
#pragma unroll
        for (int n = 0; n < 4; ++n) {
            const unsigned char* bp = Bs + (wc * 64 + n * 16 + ro) * 128;
            bq[n] = join8(*(const i32x4v*)(bp + gA),
                          *(const i32x4v*)(bp + (gA ^ 16)));
        }
#pragma unroll
        for (int m = 0; m < 4; ++m) {
            const unsigned char* ap = As + (wr * 64 + m * 16 + ro) * 128;
            const i32x8v af = join8(*(const i32x4v*)(ap + gA),
                                    *(const i32x4v*)(ap + (gA ^ 16)));
#pragma unroll
            for (int n = 0; n < 4; ++n)
                acc[m][n] = __builtin_amdgcn_mfma_scale_f32_16x16x128_f8f6f4(
                    af, bq[n], acc[m][n], 0, 0,
                    0, 0x7F7F7F7F,      // A scale = 2^0
                    0, 0x7B7B7B7B);     // B scale = 2^-4 (weights stored x16)
        }
        __syncthreads();
    }

    // epilogue: C/D frag layout col=lane&15, row=(lane>>4)*4+j  [guide m89]
    const int rbase = byh * 128 + wr * 64 + (hi << 2);
    const int cbase = bx * 128 + wc * 64 + ro;
    float bc[4];
#pragma unroll
    for (int n = 0; n < 4; ++n) bc[n] = bias[cbase + n * 16];
#pragma unroll
    for (int m = 0; m < 4; ++m) {
#pragma unroll
        for (int j = 0; j < 4; ++j) {
            const int row = rbase + m * 16 + j;
            const size_t off = (size_t)row * ldc + cbase;
            bf16_t* pd = (bf16_t*)Cp + ((row >> 14) ? 1024 : 0)
                       + (size_t)(row & 16383) * 6144 + cbase;   // EPI=4 dest
#pragma unroll
            for (int n = 0; n < 4; ++n) {
                float v = acc[m][n][j] + bc[n];
                if (EPI == 0) v = fmaxf(v, 0.0f);
                if (EPI == 2) {
                    const float u = (float)Up[off + n * 16];
                    v *= 1.0f / (1.0f + __expf(-u));
                }
                if (EPI == 3)      ((float*)Cp)[off + n * 16] = v;
                else if (EPI == 1) ((bf16_t*)Cp)[off + n * 16] = (bf16_t)v;
                else if (EPI == 4) pd[n * 16] = (bf16_t)v;
                else ((unsigned char*)Cp)[off + n * 16] = f32_to_fp8(v);
            }
        }
    }
}

// ---------------------------------------------------------------------------
// Small bf16 128x128-tile GEMM for the Wo@Wv compose; writes fp8(16*C).
// ---------------------------------------------------------------------------
__global__ __launch_bounds__(256, 2)
void gemm_small_bt(const bf16_t* __restrict__ A, int lda,
                   const bf16_t* __restrict__ W,
                   unsigned char* __restrict__ C, int ldc, int K)
{
    __shared__ bf16_t As[128 * 64];
    __shared__ bf16_t Bs[128 * 64];
    const int t = threadIdx.x;
    const int w = t >> 6, l = t & 63;
    const int wr = w >> 1, wc = w & 1;

    const bf16_t* Ab = A + (size_t)blockIdx.y * 128 * lda;
    const bf16_t* Wb = W + (size_t)blockIdx.x * 128 * K;

    const bf16_t* asrc[4];
    const bf16_t* bsrc[4];
#pragma unroll
    for (int r = 0; r < 4; ++r) {
        const int seg = r * 256 + t;
        asrc[r] = Ab + (size_t)(seg >> 3) * lda + (seg & 7) * 8;
        bsrc[r] = Wb + (size_t)(seg >> 3) * K   + (seg & 7) * 8;
    }

    f32x4 acc[4][4] = {};

    for (int kt = 0; kt < K; kt += 64) {
#pragma unroll
        for (int r = 0; r < 4; ++r) {
            GLL16(asrc[r], As + (r * 256 + w * 64) * 8);
            GLL16(bsrc[r], Bs + (r * 256 + w * 64) * 8);
            asrc[r] += 64;
            bsrc[r] += 64;
        }
        __syncthreads();
#pragma unroll
        for (int kk = 0; kk < 2; ++kk) {
            const int ro = l & 15;
            const int ko = kk * 32 + (l >> 4) * 8;
            bf16x8 af[4], bqv[4];
#pragma unroll
            for (int m = 0; m < 4; ++m)
                af[m] = *(const bf16x8*)(As + (wr * 64 + m * 16 + ro) * 64 + ko);
#pragma unroll
            for (int n = 0; n < 4; ++n)
                bqv[n] = *(const bf16x8*)(Bs + (wc * 64 + n * 16 + ro) * 64 + ko);
#pragma unroll
            for (int m = 0; m < 4; ++m)
#pragma unroll
                for (int n = 0; n < 4; ++n)
                    acc[m][n] = __builtin_amdgcn_mfma_f32_16x16x32_bf16(
                        af[m], bqv[n], acc[m][n], 0, 0, 0);
        }
        __syncthreads();
    }

    const int rbase = blockIdx.y * 128 + wr * 64 + ((l >> 4) << 2);
    const int cbase = blockIdx.x * 128 + wc * 64 + (l & 15);
#pragma unroll
    for (int m = 0; m < 4; ++m)
#pragma unroll
        for (int j = 0; j < 4; ++j) {
            const int row = rbase + m * 16 + j;
#pragma unroll
            for (int n = 0; n < 4; ++n)
                C[(size_t)row * ldc + cbase + n * 16] =
                    f32_to_fp8(acc[m][n][j] * 16.0f);
        }
}

// ---------------------------------------------------------------------------
// One merged prep dispatch (role by block range):
//  [0,4096)      : 8 MLP weights f32 -> fp8(16*w)
//  [4096,20480)  : SG/SL f32 -> fp8 (8192 blocks each)
//  [20480,21504) : Wo f32 -> bf16
//  [21504,21760) : Wv transpose+cast -> WvT bf16 (16x16 tiles of 64)
//  [21760,21776) : bias concat (g then l)
//  [21776,22800) : bvo[j] = dot(Wo[j,:], bv) + bo[j]
// ---------------------------------------------------------------------------
struct PrepArgs {
    const float* w[8];
    const float* Wo; const float* Wv;
    const float* SG; const float* SL;
    const float* bgu1; const float* bgd1;
    const float* blu1; const float* bld1;
    const float* bv;  const float* bo;
    unsigned char* Wf8; bf16_t* Wo_b; bf16_t* WvT;
    unsigned char* X; unsigned char* Y;
    float* bb; float* bvo;
};

__global__ __launch_bounds__(256)
void prep(PrepArgs a)
{
    __shared__ bf16_t tile[64][65];
    __shared__ float ws4[4];
    int b = blockIdx.x;
    const int t = threadIdx.x;

    if (b < 4096) {                                      // weights -> fp8(x16)
        const int region = b >> 9;
        const float* src = a.w[region];
        const size_t base = (size_t)(b & 511) * 2048 + t * 8;
        const float4 f0 = *(const float4*)(src + base);
        const float4 f1 = *(const float4*)(src + base + 4);
        int x = __builtin_amdgcn_cvt_pk_fp8_f32(f0.x * 16.f, f0.y * 16.f, 0, false);
        x     = __builtin_amdgcn_cvt_pk_fp8_f32(f0.z * 16.f, f0.w * 16.f, x, true);
        int y = __builtin_amdgcn_cvt_pk_fp8_f32(f1.x * 16.f, f1.y * 16.f, 0, false);
        y     = __builtin_amdgcn_cvt_pk_fp8_f32(f1.z * 16.f, f1.w * 16.f, y, true);
        *(int2*)(a.Wf8 + ((size_t)region << 20) + base) = make_int2(x, y);
        return;
    }
    b -= 4096;
    if (b < 16384) {                                     // SG/SL -> fp8
        const float* src = (b < 8192) ? a.SG : a.SL;
        unsigned char* dst = (b < 8192) ? a.X : a.Y;
        const size_t i = ((size_t)(b & 8191) * 256 + t) * 8;
        const float4 f0 = *(const float4*)(src + i);
        const float4 f1 = *(const float4*)(src + i + 4);
        int x = __builtin_amdgcn_cvt_pk_fp8_f32(f0.x, f0.y, 0, false);
        x     = __builtin_amdgcn_cvt_pk_fp8_f32(f0.z, f0.w, x, true);
        int y = __builtin_amdgcn_cvt_pk_fp8_f32(f1.x, f1.y, 0, false);
        y     = __builtin_amdgcn_cvt_pk_fp8_f32(f1.z, f1.w, y, true);
        *(int2*)(dst + i) = make_int2(x, y);
        return;
    }
    b -= 16384;
    if (b < 1024) {                                      // Wo -> bf16
        const size_t i = ((size_t)b * 256 + t) * 4;
        const float4 f = *(const float4*)(a.Wo + i);
        bf16x4 h = {(bf16_t)f.x, (bf16_t)f.y, (bf16_t)f.z, (bf16_t)f.w};
        *(bf16x4*)(a.Wo_b + i) = h;
        return;
    }
    b -= 1024;
    if (b < 256) {                                       // Wv transpose
        const int bm = (b >> 4) * 64, bk = (b & 15) * 64;
#pragma unroll
        for (int s = 0; s < 4; ++s) {
            const int r = s * 16 + (t >> 4);
            const int c = (t & 15) * 4;
            const float4 f = *(const float4*)(a.Wv + (size_t)(bm + r) * 1024 + bk + c);
            tile[r][c] = (bf16_t)f.x; tile[r][c + 1] = (bf16_t)f.y;
            tile[r][c + 2] = (bf16_t)f.z; tile[r][c + 3] = (bf16_t)f.w;
        }
        __syncthreads();
#pragma unroll
        for (int s = 0; s < 4; ++s) {
            const int k = s * 16 + (t >> 4);
            const int m = (t & 15) * 4;
            bf16x4 v = {tile[m][k], tile[m + 1][k], tile[m + 2][k], tile[m + 3][k]};
            *(bf16x4*)(a.WvT + (size_t)(bk + k) * 1024 + bm + m) = v;
        }
        return;
    }
    b -= 256;
    if (b < 16) {                                        // bias concat
        const float* pa = (b < 8) ? a.bgu1 : a.blu1;
        const float* pb = (b < 8) ? a.bgd1 : a.bld1;
        float* dst = a.bb + ((b < 8) ? 0 : 2048);
        const int i = (b & 7) * 256 + t;
        if (i < 1024) dst[i] = pa[i];
        else dst[i] = pb[i - 1024];
        return;
    }
    b -= 16;
    {                                                    // bias_compose, j = b
        const float* wr = a.Wo + (size_t)b * 1024;
        float s = 0.0f;
#pragma unroll
        for (int i = 0; i < 4; ++i) s += wr[t + i * 256] * a.bv[t + i * 256];
#pragma unroll
        for (int o = 32; o > 0; o >>= 1) s += __shfl_down(s, o);
        if ((t & 63) == 0) ws4[t >> 6] = s;
        __syncthreads();
        if (t == 0) a.bvo[b] = ws4[0] + ws4[1] + ws4[2] + ws4[3] + a.bo[b];
    }
}

// ---------------------------------------------------------------------------
// One block per row. Inputs: P (bf16 pre-norm, interleaved at the head of
// this row's O1 slot: sg at [0,1024), sl at [1024,2048) bf16). Reads P into
// registers, barriers, then: dual l2norm + sigmoid gate + exact top-80
// (radix select, stable lowest-index ties) + O1 = [vis | sparse] + OUT2/OUT3.
// ---------------------------------------------------------------------------
__global__ __launch_bounds__(256)
void finalize_topk(float* __restrict__ OUT2, float* __restrict__ OUT3,
                   const float* __restrict__ VIS, float* __restrict__ O1)
{
    const int row = blockIdx.x, t = threadIdx.x;
    __shared__ int bins[256];
    __shared__ float wred[8];
    __shared__ int wsum[4];
    __shared__ int s_sel, s_kk;

    float* o1r = O1 + (size_t)row * 3072;
    const bf16_t* prow = (const bf16_t*)o1r;
    float av[4], lv[4];
    {
        const bf16x4 pg = *(const bf16x4*)(prow + t * 4);
        const bf16x4 pl = *(const bf16x4*)(prow + 1024 + t * 4);
#pragma unroll
        for (int j = 0; j < 4; ++j) { av[j] = (float)pg[j]; lv[j] = (float)pl[j]; }
    }
    __syncthreads();   // all P reads complete before o1r is overwritten

    float sa = 0.0f, sb = 0.0f;
#pragma unroll
    for (int j = 0; j < 4; ++j) { sa += av[j] * av[j]; sb += lv[j] * lv[j]; }
#pragma unroll
    for (int o = 32; o > 0; o >>= 1) {
        sa += __shfl_down(sa, o);
        sb += __shfl_down(sb, o);
    }
    if ((t & 63) == 0) { wred[t >> 6] = sa; wred[4 + (t >> 6)] = sb; }
    __syncthreads();
    const float sca = 1.0f / fmaxf(sqrtf(wred[0] + wred[1] + wred[2] + wred[3]), 1e-12f);
    const float scl = 1.0f / fmaxf(sqrtf(wred[4] + wred[5] + wred[6] + wred[7]), 1e-12f);

    float fv[4], f2v[4];
    unsigned ab[4];
#pragma unroll
    for (int j = 0; j < 4; ++j) {
        const float f2 = lv[j] * scl;
        const float f1 = av[j] * sca;
        const float fin = f2 / (1.0f + __expf(-f1));   // sigmoid(f1)*f2
        f2v[j] = f2; fv[j] = fin;
        ab[j] = __float_as_uint(fin) & 0x7fffffffu;
    }
    *(float4*)(OUT3 + (size_t)row * 1024 + t * 4) =
        make_float4(f2v[0], f2v[1], f2v[2], f2v[3]);
    *(float4*)(OUT2 + (size_t)row * 1024 + t * 4) =
        make_float4(fv[0], fv[1], fv[2], fv[3]);

    const float* vr = VIS + (size_t)row * 2048;
    *(float4*)(o1r + t * 4)        = *(const float4*)(vr + t * 4);
    *(float4*)(o1r + 1024 + t * 4) = *(const float4*)(vr + 1024 + t * 4);

    // --- radix select: exact bits of the 80th-largest |fin| ---
    unsigned pref = 0u, msk = 0u;
    int kk = 80;
    for (int bp = 3; bp >= 0; --bp) {
        bins[t] = 0;
        __syncthreads();
#pragma unroll
        for (int j = 0; j < 4; ++j)
            if ((ab[j] & msk) == pref)
                atomicAdd(&bins[(ab[j] >> (bp * 8)) & 255], 1);
        __syncthreads();
        const int x = bins[t];
        int p = x;
#pragma unroll
        for (int o = 1; o < 64; o <<= 1) {
            const int y = __shfl_up(p, o);
            if ((t & 63) >= o) p += y;
        }
        if ((t & 63) == 63) wsum[t >> 6] = p;
        __syncthreads();
        const int tot = wsum[0] + wsum[1] + wsum[2] + wsum[3];
        int off = 0;
        if ((t >> 6) > 0) off += wsum[0];
        if ((t >> 6) > 1) off += wsum[1];
        if ((t >> 6) > 2) off += wsum[2];
        p += off;                              // inclusive prefix over 256
        const int Sme = tot - p + x;           // suffix sum incl. bin t
        const int Snx = tot - p;               // suffix sum from bin t+1
        if (Sme >= kk && Snx < kk) { s_sel = t; s_kk = kk - Snx; }
        __syncthreads();
        pref |= (unsigned)s_sel << (bp * 8);
        msk  |= 0xFFu << (bp * 8);
        kk = s_kk;
        __syncthreads();
    }

    // stable tie-break: keep first kk elements equal to threshold (index order)
    int ec = 0;
#pragma unroll
    for (int j = 0; j < 4; ++j) ec += (ab[j] == pref) ? 1 : 0;
    int pe = ec;
#pragma unroll
    for (int o = 1; o < 64; o <<= 1) {
        const int y = __shfl_up(pe, o);
        if ((t & 63) >= o) pe += y;
    }
    if ((t & 63) == 63) wsum[t >> 6] = pe;
    __syncthreads();
    int off2 = 0;
    if ((t >> 6) > 0) off2 += wsum[0];
    if ((t >> 6) > 1) off2 += wsum[1];
    if ((t >> 6) > 2) off2 += wsum[2];
    int excl = pe + off2 - ec;
#pragma unroll
    for (int j = 0; j < 4; ++j) {
        const bool eq = (ab[j] == pref);
        const bool kp = (ab[j] > pref) || (eq && (excl < kk));
        o1r[2048 + t * 4 + j] = kp ? fv[j] : 0.0f;
        if (eq) ++excl;
    }
}

// ---------------------------------------------------------------------------
extern "C" void kernel_launch(void* const* d_in, const int* in_sizes, int n_in,
                              void* d_out, int out_size, void* d_ws, size_t ws_size,
                              hipStream_t stream)
{
    const float* SG   = (const float*)d_in[0];
    const float* SL   = (const float*)d_in[1];
    const float* VIS  = (const float*)d_in[2];
    const float* Wgu1 = (const float*)d_in[3];
    const float* bgu1 = (const float*)d_in[4];
    const float* Wgu2 = (const float*)d_in[5];  const float* bgu2 = (const float*)d_in[6];
    const float* Wgd1 = (const float*)d_in[7];  const float* bgd1 = (const float*)d_in[8];
    const float* Wgd2 = (const float*)d_in[9];  const float* bgd2 = (const float*)d_in[10];
    const float* Wlu1 = (const float*)d_in[11]; const float* blu1 = (const float*)d_in[12];
    const float* Wlu2 = (const float*)d_in[13]; const float* blu2 = (const float*)d_in[14];
    const float* Wld1 = (const float*)d_in[15]; const float* bld1 = (const float*)d_in[16];
    const float* Wld2 = (const float*)d_in[17]; const float* bld2 = (const float*)d_in[18];
    const float* Wo   = (const float*)d_in[19]; const float* bo   = (const float*)d_in[20];
    const float* Win  = (const float*)d_in[21]; const float* bin_ = (const float*)d_in[22];
    const float* Wv = Win + (size_t)2 * 1024 * 1024;   // Win[2E:]
    const float* bv = bin_ + 2048;

    float* OUT1 = (float*)d_out;                         // B x 3072
    float* OUT2 = OUT1 + (size_t)16384 * 3072;           // B x 1024 (final)
    float* OUT3 = OUT2 + (size_t)16384 * 1024;           // B x 1024 (f2)

    // ws: fp8 weights (8 MLP, x16) + bf16 Wo + fp8 Wvo(x16) + biases (~12 MB)
    char* ws = (char*)d_ws;
    unsigned char* Wf8 = (unsigned char*)ws;             // [0, 8M)
    bf16_t* Wo_b = (bf16_t*)(ws + (8u << 20));           // [8M, 10M)
    unsigned char* Wvo = (unsigned char*)(ws + (10u << 20)); // [10M, 11M)
    float* bb  = (float*)(ws + (11u << 20));             // 4096 f32
    float* bvo = bb + 4096;                              // 1024 f32

    // scratch inside d_out (320 MiB), lifetime-checked:
    //   Ug [64,96)M  Ul [96,128)M bf16 : D2 out, D3 in (dead before D45)
    //   H1g [128,160)M  H1l [160,192)M fp8 : D1 out, D2/D3 in (dead after D3)
    //   WvT (2MB bf16) transient in H1g slot pre-D1.
    //   X [192,208)M  Y [208,224)M fp8 : prep out (sg/sl), D1 in; D3 rewrites
    //     as sg'/sl'; D45 reads; region = OUT2's first 32M, which finalize
    //     writes only AFTER D45 consumed X/Y.
    //   D45 (EPI=4) writes bf16 P interleaved at the head of each O1 row
    //     [0,192)M; finalize reads P (regs), barriers, overwrites O1 row.
    bf16_t* Ug  = (bf16_t*)((char*)d_out + (64u << 20));
    bf16_t* Ul  = (bf16_t*)((char*)d_out + (96u << 20));
    unsigned char* H1g = (unsigned char*)d_out + (128u << 20);
    unsigned char* H1l = H1g + (32u << 20);
    bf16_t* WvT = (bf16_t*)H1g;                          // transient, pre-D1
    unsigned char* X = (unsigned char*)d_out + (192u << 20);
    unsigned char* Y = X + (16u << 20);

    PrepArgs pa;
    pa.w[0] = Wgu1; pa.w[1] = Wgd1; pa.w[2] = Wlu1; pa.w[3] = Wld1;
    pa.w[4] = Wgu2; pa.w[5] = Wgd2; pa.w[6] = Wlu2; pa.w[7] = Wld2;
    pa.Wo = Wo; pa.Wv = Wv; pa.SG = SG; pa.SL = SL;
    pa.bgu1 = bgu1; pa.bgd1 = bgd1; pa.blu1 = blu1; pa.bld1 = bld1;
    pa.bv = bv; pa.bo = bo;
    pa.Wf8 = Wf8; pa.Wo_b = Wo_b; pa.WvT = WvT;
    pa.X = X; pa.Y = Y; pa.bb = bb; pa.bvo = bvo;

    prep<<<22800, 256, 0, stream>>>(pa);

    // Wvo = fp8(16 * Wo @ Wv)
    gemm_small_bt<<<dim3(8, 8), 256, 0, stream>>>(Wo_b, 1024, WvT, Wvo, 1024, 1024);

    unsigned char* Wg1   = Wf8;                          // [Wgu1;Wgd1] 2048x1024
    unsigned char* Wl1   = Wf8 + (size_t)2 * 1048576;    // [Wlu1;Wld1]
    unsigned char* Wgu2b = Wf8 + (size_t)4 * 1048576;
    unsigned char* Wgd2b = Wf8 + (size_t)5 * 1048576;
    unsigned char* Wlu2b = Wf8 + (size_t)6 * 1048576;
    unsigned char* Wld2b = Wf8 + (size_t)7 * 1048576;

    // D1: h1 = relu([X;Y] @ [W?u1;W?d1]^T + b) -> fp8. N=2048 per half.
    gemm128_f8<0><<<4096, 256, 0, stream>>>(X, Y, 1024, Wg1, Wl1, bb, bb + 2048,
                                            nullptr, nullptr, H1g, H1l, 2048, 1024, 16, 128, 32);
    // D2: U = h1[:, :1024] @ W?u2^T + b -> bf16 (gate pre-act)
    gemm128_f8<1><<<2048, 256, 0, stream>>>(H1g, H1l, 2048, Wgu2b, Wlu2b, bgu2, blu2,
                                            nullptr, nullptr, Ug, Ul, 1024, 1024, 8, 128, 16);
    // D3: s? = sigmoid(U) * (h1[:, 1024:] @ W?d2^T + b) -> fp8 into X, Y
    gemm128_f8<2><<<2048, 256, 0, stream>>>(H1g + 1024, H1l + 1024, 2048, Wgd2b, Wld2b,
                                            bgd2, bld2, Ug, Ul, X, Y, 1024, 1024, 8, 128, 16);
    // D45: pre-norm attn_out = [sg;sl] @ Wvo^T + bvo -> bf16 P in O1 rows
    gemm128_f8<4><<<2048, 256, 0, stream>>>(X, X, 1024, Wvo, Wvo, bvo, bvo,
                                            nullptr, nullptr, OUT1, OUT1, 6144, 1024, 8, 256, 8);

    finalize_topk<<<16384, 256, 0, stream>>>(OUT2, OUT3, VIS, OUT1);
}

// Round 11
// 386.533 us; speedup vs baseline: 1.6659x; 1.0449x over previous
//
#include <hip/hip_runtime.h>

typedef __bf16 bf16_t;
typedef __bf16 bf16x4 __attribute__((ext_vector_type(4)));
typedef __bf16 bf16x8 __attribute__((ext_vector_type(8)));
typedef float f32x4 __attribute__((ext_vector_type(4)));
typedef int i32x4v __attribute__((ext_vector_type(4)));
typedef int i32x8v __attribute__((ext_vector_type(8)));

#define GLL16(gp, lp) __builtin_amdgcn_global_load_lds( \
    (__attribute__((address_space(1))) void*)(gp),      \
    (__attribute__((address_space(3))) void*)(lp), 16, 0, 0)

__device__ inline unsigned char f32_to_fp8(float v)
{
    return (unsigned char)(__builtin_amdgcn_cvt_pk_fp8_f32(v, v, 0, false) & 0xff);
}

__device__ inline i32x8v join8(i32x4v a, i32x4v b)
{
    i32x8v r;
    r[0] = a[0]; r[1] = a[1]; r[2] = a[2]; r[3] = a[3];
    r[4] = b[0]; r[5] = b[1]; r[6] = b[2]; r[7] = b[3];
    return r;
}

// ---------------------------------------------------------------------------
// 128x128-tile MX-fp8 GEMM, m97 structure (r9/r10-verified), BK=128.
//   C[half][M,N] = epi(A[half][M,K] @ W[half][N,K]^T + bias[half])
// 256 threads (4 waves 2x2); 32 KiB LDS single-buffered; 2 barriers/K-tile;
// cross-block overlap covers the staging drain (m97/m114).
// r11: staging addresses = ONE per-lane base + wave-uniform offsets.
//   granule g = r*256+t -> row = r*32 + (t>>3); since 32r % 8 == 0 the
//   swizzled col cg = (t&7)^((t>>3)&7) is r-independent, so
//   addr = base + r*32*ld + koff (uniform part folds to SGPR) -> ~12 fewer
//   VGPRs -> fits the 4-waves/EU bin -> __launch_bounds__(256,4), 4 blk/CU.
// MFMA: mfma_scale_f32_16x16x128_f8f6f4, fp8 e4m3 both operands.
// UNIFORM scales: A 2^0 (0x7F); weights stored fp8(16*W), B-scale 2^-4 (0x7B).
// Swizzle: 16B-granule XOR row&7 both-sides. Epilogue n-innermost.
// XCD windows: 8-byh x 4-c.
// EPI: 0 relu->fp8, 1 bias->bf16, 2 sigmoid(U)*v->fp8, 3 bias->f32,
//      4 bias->bf16 interleaved into O1 rows (half h row r ->
//        (bf16*)O1 + r*6144 + h*1024)
// ---------------------------------------------------------------------------
template<int EPI>
__global__ __launch_bounds__(256, 4)
void gemm128_f8(const unsigned char* __restrict__ A0,
                const unsigned char* __restrict__ A1, int lda,
                const unsigned char* __restrict__ W0,
                const unsigned char* __restrict__ W1,
                const float* __restrict__ bias0, const float* __restrict__ bias1,
                const bf16_t* __restrict__ U0, const bf16_t* __restrict__ U1,
                void* __restrict__ C0v, void* __restrict__ C1v, int ldc,
                int K, int nbx, int nbyH, int ctot)
{
    __shared__ __attribute__((aligned(64))) unsigned char As[128 * 128];
    __shared__ __attribute__((aligned(64))) unsigned char Bs[128 * 128];

    const int t = threadIdx.x;
    const int w = t >> 6, l = t & 63;
    const int wr = w >> 1, wc = w & 1;        // 2 x 2 wave grid
    const int ro = l & 15, hi = l >> 4;
    const int sw = ro & 7;
    const int gA = (((hi << 1) ^ sw) * 16);   // first 16B granule byte offset

    // XCD-window remap (gridDim%8==0, nbyH%8==0, ctot%4==0)
    const int xcd   = blockIdx.x & 7;
    const int local = blockIdx.x >> 3;
    const int wpb   = ctot >> 2;
    const int win   = local >> 5;
    const int r5    = local & 31;
    const int strp  = win / wpb;
    const int wcn   = win - strp * wpb;
    const int byh   = xcd * (nbyH >> 3) + strp * 8 + (r5 >> 2);
    const int c     = wcn * 4 + (r5 & 3);
    const int sel   = (c >= nbx) ? 1 : 0;
    const int bx    = c - sel * nbx;

    const unsigned char* A    = sel ? A1 : A0;
    const unsigned char* W    = sel ? W1 : W0;
    const float*  bias = sel ? bias1 : bias0;
    const bf16_t* Up   = sel ? U1 : U0;
    void*         Cp   = sel ? C1v : C0v;

    const unsigned char* Ab = A + (size_t)byh * 128 * lda;
    const unsigned char* Wb = W + (size_t)bx * 128 * K;

    // single per-lane staging base; r-offsets are wave-uniform (fold to SGPR)
    const int trow = t >> 3;
    const int cg   = (t & 7) ^ (trow & 7);    // inverse of ds_read swizzle
    const unsigned char* asrc = Ab + (size_t)trow * lda + cg * 16;
    const unsigned char* bsrc = Wb + (size_t)trow * K   + cg * 16;
    int koff = 0;

    f32x4 acc[4][4] = {};

    for (int kt = 0; kt < K; kt += 128) {
#pragma unroll
        for (int r = 0; r < 4; ++r) {
            GLL16(asrc + (size_t)r * 32 * lda + koff, &As[(r * 256 + w * 64) * 16]);
            GLL16(bsrc + (size_t)r * 32 * K   + koff, &Bs[(r * 256 + w * 64) * 16]);
        }
        koff += 128;
        __syncthreads();
        i32x8v bq[4];
#pragma unroll
        for (int n = 0; n < 4; ++n) {
            const unsigned char* bp = Bs + (wc * 64 + n * 16 + ro) * 128;
            bq[n] = join8(*(const i32x4v*)(bp + gA),
                          *(const i32x4v*)(bp + (gA ^ 16)));
        }
#pragma unroll
        for (int m = 0; m < 4; ++m) {
            const unsigned char* ap = As + (wr * 64 + m * 16 + ro) * 128;
            const i32x8v af = join8(*(const i32x4v*)(ap + gA),
                                    *(const i32x4v*)(ap + (gA ^ 16)));
#pragma unroll
            for (int n = 0; n < 4; ++n)
                acc[m][n] = __builtin_amdgcn_mfma_scale_f32_16x16x128_f8f6f4(
                    af, bq[n], acc[m][n], 0, 0,
                    0, 0x7F7F7F7F,      // A scale = 2^0
                    0, 0x7B7B7B7B);     // B scale = 2^-4 (weights stored x16)
        }
        __syncthreads();
    }

    // epilogue: C/D frag layout col=lane&15, row=(lane>>4)*4+j  [guide m89]
    const int rbase = byh * 128 + wr * 64 + (hi << 2);
    const int cbase = bx * 128 + wc * 64 + ro;
    float bc[4];
#pragma unroll
    for (int n = 0; n < 4; ++n) bc[n] = bias[cbase + n * 16];
#pragma unroll
    for (int m = 0; m < 4; ++m) {
#pragma unroll
        for (int j = 0; j < 4; ++j) {
            const int row = rbase + m * 16 + j;
            const size_t off = (size_t)row * ldc + cbase;
            bf16_t* pd = (bf16_t*)Cp + ((row >> 14) ? 1024 : 0)
                       + (size_t)(row & 16383) * 6144 + cbase;   // EPI=4 dest
#pragma unroll
            for (int n = 0; n < 4; ++n) {
                float v = acc[m][n][j] + bc[n];
                if (EPI == 0) v = fmaxf(v, 0.0f);
                if (EPI == 2) {
                    const float u = (float)Up[off + n * 16];
                    v *= 1.0f / (1.0f + __expf(-u));
                }
                if (EPI == 3)      ((float*)Cp)[off + n * 16] = v;
                else if (EPI == 1) ((bf16_t*)Cp)[off + n * 16] = (bf16_t)v;
                else if (EPI == 4) pd[n * 16] = (bf16_t)v;
                else ((unsigned char*)Cp)[off + n * 16] = f32_to_fp8(v);
            }
        }
    }
}

// ---------------------------------------------------------------------------
// Small bf16 128x128-tile GEMM for the Wo@Wv compose; writes fp8(16*C).
// ---------------------------------------------------------------------------
__global__ __launch_bounds__(256, 2)
void gemm_small_bt(const bf16_t* __restrict__ A, int lda,
                   const bf16_t* __restrict__ W,
                   unsigned char* __restrict__ C, int ldc, int K)
{
    __shared__ bf16_t As[128 * 64];
    __shared__ bf16_t Bs[128 * 64];
    const int t = threadIdx.x;
    const int w = t >> 6, l = t & 63;
    const int wr = w >> 1, wc = w & 1;

    const bf16_t* Ab = A + (size_t)blockIdx.y * 128 * lda;
    const bf16_t* Wb = W + (size_t)blockIdx.x * 128 * K;

    const bf16_t* asrc[4];
    const bf16_t* bsrc[4];
#pragma unroll
    for (int r = 0; r < 4; ++r) {
        const int seg = r * 256 + t;
        asrc[r] = Ab + (size_t)(seg >> 3) * lda + (seg & 7) * 8;
        bsrc[r] = Wb + (size_t)(seg >> 3) * K   + (seg & 7) * 8;
    }

    f32x4 acc[4][4] = {};

    for (int kt = 0; kt < K; kt += 64) {
#pragma unroll
        for (int r = 0; r < 4; ++r) {
            GLL16(asrc[r], As + (r * 256 + w * 64) * 8);
            GLL16(bsrc[r], Bs + (r * 256 + w * 64) * 8);
            asrc[r] += 64;
            bsrc[r] += 64;
        }
        __syncthreads();
#pragma unroll
        for (int kk = 0; kk < 2; ++kk) {
            const int ro = l & 15;
            const int ko = kk * 32 + (l >> 4) * 8;
            bf16x8 af[4], bqv[4];
#pragma unroll
            for (int m = 0; m < 4; ++m)
                af[m] = *(const bf16x8*)(As + (wr * 64 + m * 16 + ro) * 64 + ko);
#pragma unroll
            for (int n = 0; n < 4; ++n)
                bqv[n] = *(const bf16x8*)(Bs + (wc * 64 + n * 16 + ro) * 64 + ko);
#pragma unroll
            for (int m = 0; m < 4; ++m)
#pragma unroll
                for (int n = 0; n < 4; ++n)
                    acc[m][n] = __builtin_amdgcn_mfma_f32_16x16x32_bf16(
                        af[m], bqv[n], acc[m][n], 0, 0, 0);
        }
        __syncthreads();
    }

    const int rbase = blockIdx.y * 128 + wr * 64 + ((l >> 4) << 2);
    const int cbase = blockIdx.x * 128 + wc * 64 + (l & 15);
#pragma unroll
    for (int m = 0; m < 4; ++m)
#pragma unroll
        for (int j = 0; j < 4; ++j) {
            const int row = rbase + m * 16 + j;
#pragma unroll
            for (int n = 0; n < 4; ++n)
                C[(size_t)row * ldc + cbase + n * 16] =
                    f32_to_fp8(acc[m][n][j] * 16.0f);
        }
}

// ---------------------------------------------------------------------------
// One merged prep dispatch (role by block range):
//  [0,4096)      : 8 MLP weights f32 -> fp8(16*w)
//  [4096,20480)  : SG/SL f32 -> fp8 (8192 blocks each)
//  [20480,21504) : Wo f32 -> bf16
//  [21504,21760) : Wv transpose+cast -> WvT bf16 (16x16 tiles of 64)
//  [21760,21776) : bias concat (g then l)
//  [21776,22800) : bvo[j] = dot(Wo[j,:], bv) + bo[j]
// ---------------------------------------------------------------------------
struct PrepArgs {
    const float* w[8];
    const float* Wo; const float* Wv;
    const float* SG; const float* SL;
    const float* bgu1; const float* bgd1;
    const float* blu1; const float* bld1;
    const float* bv;  const float* bo;
    unsigned char* Wf8; bf16_t* Wo_b; bf16_t* WvT;
    unsigned char* X; unsigned char* Y;
    float* bb; float* bvo;
};

__global__ __launch_bounds__(256)
void prep(PrepArgs a)
{
    __shared__ bf16_t tile[64][65];
    __shared__ float ws4[4];
    int b = blockIdx.x;
    const int t = threadIdx.x;

    if (b < 4096) {                                      // weights -> fp8(x16)
        const int region = b >> 9;
        const float* src = a.w[region];
        const size_t base = (size_t)(b & 511) * 2048 + t * 8;
        const float4 f0 = *(const float4*)(src + base);
        const float4 f1 = *(const float4*)(src + base + 4);
        int x = __builtin_amdgcn_cvt_pk_fp8_f32(f0.x * 16.f, f0.y * 16.f, 0, false);
        x     = __builtin_amdgcn_cvt_pk_fp8_f32(f0.z * 16.f, f0.w * 16.f, x, true);
        int y = __builtin_amdgcn_cvt_pk_fp8_f32(f1.x * 16.f, f1.y * 16.f, 0, false);
        y     = __builtin_amdgcn_cvt_pk_fp8_f32(f1.z * 16.f, f1.w * 16.f, y, true);
        *(int2*)(a.Wf8 + ((size_t)region << 20) + base) = make_int2(x, y);
        return;
    }
    b -= 4096;
    if (b < 16384) {                                     // SG/SL -> fp8
        const float* src = (b < 8192) ? a.SG : a.SL;
        unsigned char* dst = (b < 8192) ? a.X : a.Y;
        const size_t i = ((size_t)(b & 8191) * 256 + t) * 8;
        const float4 f0 = *(const float4*)(src + i);
        const float4 f1 = *(const float4*)(src + i + 4);
        int x = __builtin_amdgcn_cvt_pk_fp8_f32(f0.x, f0.y, 0, false);
        x     = __builtin_amdgcn_cvt_pk_fp8_f32(f0.z, f0.w, x, true);
        int y = __builtin_amdgcn_cvt_pk_fp8_f32(f1.x, f1.y, 0, false);
        y     = __builtin_amdgcn_cvt_pk_fp8_f32(f1.z, f1.w, y, true);
        *(int2*)(dst + i) = make_int2(x, y);
        return;
    }
    b -= 16384;
    if (b < 1024) {                                      // Wo -> bf16
        const size_t i = ((size_t)b * 256 + t) * 4;
        const float4 f = *(const float4*)(a.Wo + i);
        bf16x4 h = {(bf16_t)f.x, (bf16_t)f.y, (bf16_t)f.z, (bf16_t)f.w};
        *(bf16x4*)(a.Wo_b + i) = h;
        return;
    }
    b -= 1024;
    if (b < 256) {                                       // Wv transpose
        const int bm = (b >> 4) * 64, bk = (b & 15) * 64;
#pragma unroll
        for (int s = 0; s < 4; ++s) {
            const int r = s * 16 + (t >> 4);
            const int c = (t & 15) * 4;
            const float4 f = *(const float4*)(a.Wv + (size_t)(bm + r) * 1024 + bk + c);
            tile[r][c] = (bf16_t)f.x; tile[r][c + 1] = (bf16_t)f.y;
            tile[r][c + 2] = (bf16_t)f.z; tile[r][c + 3] = (bf16_t)f.w;
        }
        __syncthreads();
#pragma unroll
        for (int s = 0; s < 4; ++s) {
            const int k = s * 16 + (t >> 4);
            const int m = (t & 15) * 4;
            bf16x4 v = {tile[m][k], tile[m + 1][k], tile[m + 2][k], tile[m + 3][k]};
            *(bf16x4*)(a.WvT + (size_t)(bk + k) * 1024 + bm + m) = v;
        }
        return;
    }
    b -= 256;
    if (b < 16) {                                        // bias concat
        const float* pa = (b < 8) ? a.bgu1 : a.blu1;
        const float* pb = (b < 8) ? a.bgd1 : a.bld1;
        float* dst = a.bb + ((b < 8) ? 0 : 2048);
        const int i = (b & 7) * 256 + t;
        if (i < 1024) dst[i] = pa[i];
        else dst[i] = pb[i - 1024];
        return;
    }
    b -= 16;
    {                                                    // bias_compose, j = b
        const float* wr = a.Wo + (size_t)b * 1024;
        float s = 0.0f;
#pragma unroll
        for (int i = 0; i < 4; ++i) s += wr[t + i * 256] * a.bv[t + i * 256];
#pragma unroll
        for (int o = 32; o > 0; o >>= 1) s += __shfl_down(s, o);
        if ((t & 63) == 0) ws4[t >> 6] = s;
        __syncthreads();
        if (t == 0) a.bvo[b] = ws4[0] + ws4[1] + ws4[2] + ws4[3] + a.bo[b];
    }
}

// ---------------------------------------------------------------------------
// One block per row. Inputs: P (bf16 pre-norm, interleaved at the head of
// this row's O1 slot: sg at [0,1024), sl at [1024,2048) bf16). Reads P into
// registers, barriers, then: dual l2norm + sigmoid gate + exact top-80
// (radix select, stable lowest-index ties) + O1 = [vis | sparse] + OUT2/OUT3.
// ---------------------------------------------------------------------------
__global__ __launch_bounds__(256)
void finalize_topk(float* __restrict__ OUT2, float* __restrict__ OUT3,
                   const float* __restrict__ VIS, float* __restrict__ O1)
{
    const int row = blockIdx.x, t = threadIdx.x;
    __shared__ int bins[256];
    __shared__ float wred[8];
    __shared__ int wsum[4];
    __shared__ int s_sel, s_kk;

    float* o1r = O1 + (size_t)row * 3072;
    const bf16_t* prow = (const bf16_t*)o1r;
    float av[4], lv[4];
    {
        const bf16x4 pg = *(const bf16x4*)(prow + t * 4);
        const bf16x4 pl = *(const bf16x4*)(prow + 1024 + t * 4);
#pragma unroll
        for (int j = 0; j < 4; ++j) { av[j] = (float)pg[j]; lv[j] = (float)pl[j]; }
    }
    __syncthreads();   // all P reads complete before o1r is overwritten

    float sa = 0.0f, sb = 0.0f;
#pragma unroll
    for (int j = 0; j < 4; ++j) { sa += av[j] * av[j]; sb += lv[j] * lv[j]; }
#pragma unroll
    for (int o = 32; o > 0; o >>= 1) {
        sa += __shfl_down(sa, o);
        sb += __shfl_down(sb, o);
    }
    if ((t & 63) == 0) { wred[t >> 6] = sa; wred[4 + (t >> 6)] = sb; }
    __syncthreads();
    const float sca = 1.0f / fmaxf(sqrtf(wred[0] + wred[1] + wred[2] + wred[3]), 1e-12f);
    const float scl = 1.0f / fmaxf(sqrtf(wred[4] + wred[5] + wred[6] + wred[7]), 1e-12f);

    float fv[4], f2v[4];
    unsigned ab[4];
#pragma unroll
    for (int j = 0; j < 4; ++j) {
        const float f2 = lv[j] * scl;
        const float f1 = av[j] * sca;
        const float fin = f2 / (1.0f + __expf(-f1));   // sigmoid(f1)*f2
        f2v[j] = f2; fv[j] = fin;
        ab[j] = __float_as_uint(fin) & 0x7fffffffu;
    }
    *(float4*)(OUT3 + (size_t)row * 1024 + t * 4) =
        make_float4(f2v[0], f2v[1], f2v[2], f2v[3]);
    *(float4*)(OUT2 + (size_t)row * 1024 + t * 4) =
        make_float4(fv[0], fv[1], fv[2], fv[3]);

    const float* vr = VIS + (size_t)row * 2048;
    *(float4*)(o1r + t * 4)        = *(const float4*)(vr + t * 4);
    *(float4*)(o1r + 1024 + t * 4) = *(const float4*)(vr + 1024 + t * 4);

    // --- radix select: exact bits of the 80th-largest |fin| ---
    unsigned pref = 0u, msk = 0u;
    int kk = 80;
    for (int bp = 3; bp >= 0; --bp) {
        bins[t] = 0;
        __syncthreads();
#pragma unroll
        for (int j = 0; j < 4; ++j)
            if ((ab[j] & msk) == pref)
                atomicAdd(&bins[(ab[j] >> (bp * 8)) & 255], 1);
        __syncthreads();
        const int x = bins[t];
        int p = x;
#pragma unroll
        for (int o = 1; o < 64; o <<= 1) {
            const int y = __shfl_up(p, o);
            if ((t & 63) >= o) p += y;
        }
        if ((t & 63) == 63) wsum[t >> 6] = p;
        __syncthreads();
        const int tot = wsum[0] + wsum[1] + wsum[2] + wsum[3];
        int off = 0;
        if ((t >> 6) > 0) off += wsum[0];
        if ((t >> 6) > 1) off += wsum[1];
        if ((t >> 6) > 2) off += wsum[2];
        p += off;                              // inclusive prefix over 256
        const int Sme = tot - p + x;           // suffix sum incl. bin t
        const int Snx = tot - p;               // suffix sum from bin t+1
        if (Sme >= kk && Snx < kk) { s_sel = t; s_kk = kk - Snx; }
        __syncthreads();
        pref |= (unsigned)s_sel << (bp * 8);
        msk  |= 0xFFu << (bp * 8);
        kk = s_kk;
        __syncthreads();
    }

    // stable tie-break: keep first kk elements equal to threshold (index order)
    int ec = 0;
#pragma unroll
    for (int j = 0; j < 4; ++j) ec += (ab[j] == pref) ? 1 : 0;
    int pe = ec;
#pragma unroll
    for (int o = 1; o < 64; o <<= 1) {
        const int y = __shfl_up(pe, o);
        if ((t & 63) >= o) pe += y;
    }
    if ((t & 63) == 63) wsum[t >> 6] = pe;
    __syncthreads();
    int off2 = 0;
    if ((t >> 6) > 0) off2 += wsum[0];
    if ((t >> 6) > 1) off2 += wsum[1];
    if ((t >> 6) > 2) off2 += wsum[2];
    int excl = pe + off2 - ec;
#pragma unroll
    for (int j = 0; j < 4; ++j) {
        const bool eq = (ab[j] == pref);
        const bool kp = (ab[j] > pref) || (eq && (excl < kk));
        o1r[2048 + t * 4 + j] = kp ? fv[j] : 0.0f;
        if (eq) ++excl;
    }
}

// ---------------------------------------------------------------------------
extern "C" void kernel_launch(void* const* d_in, const int* in_sizes, int n_in,
                              void* d_out, int out_size, void* d_ws, size_t ws_size,
                              hipStream_t stream)
{
    const float* SG   = (const float*)d_in[0];
    const float* SL   = (const float*)d_in[1];
    const float* VIS  = (const float*)d_in[2];
    const float* Wgu1 = (const float*)d_in[3];
    const float* bgu1 = (const float*)d_in[4];
    const float* Wgu2 = (const float*)d_in[5];  const float* bgu2 = (const float*)d_in[6];
    const float* Wgd1 = (const float*)d_in[7];  const float* bgd1 = (const float*)d_in[8];
    const float* Wgd2 = (const float*)d_in[9];  const float* bgd2 = (const float*)d_in[10];
    const float* Wlu1 = (const float*)d_in[11]; const float* blu1 = (const float*)d_in[12];
    const float* Wlu2 = (const float*)d_in[13]; const float* blu2 = (const float*)d_in[14];
    const float* Wld1 = (const float*)d_in[15]; const float* bld1 = (const float*)d_in[16];
    const float* Wld2 = (const float*)d_in[17]; const float* bld2 = (const float*)d_in[18];
    const float* Wo   = (const float*)d_in[19]; const float* bo   = (const float*)d_in[20];
    const float* Win  = (const float*)d_in[21]; const float* bin_ = (const float*)d_in[22];
    const float* Wv = Win + (size_t)2 * 1024 * 1024;   // Win[2E:]
    const float* bv = bin_ + 2048;

    float* OUT1 = (float*)d_out;                         // B x 3072
    float* OUT2 = OUT1 + (size_t)16384 * 3072;           // B x 1024 (final)
    float* OUT3 = OUT2 + (size_t)16384 * 1024;           // B x 1024 (f2)

    // ws: fp8 weights (8 MLP, x16) + bf16 Wo + fp8 Wvo(x16) + biases (~12 MB)
    char* ws = (char*)d_ws;
    unsigned char* Wf8 = (unsigned char*)ws;             // [0, 8M)
    bf16_t* Wo_b = (bf16_t*)(ws + (8u << 20));           // [8M, 10M)
    unsigned char* Wvo = (unsigned char*)(ws + (10u << 20)); // [10M, 11M)
    float* bb  = (float*)(ws + (11u << 20));             // 4096 f32
    float* bvo = bb + 4096;                              // 1024 f32

    // scratch inside d_out (320 MiB), lifetime-checked (r10 layout):
    //   Ug [64,96)M  Ul [96,128)M bf16 : D2 out, D3 in
    //   H1g [128,160)M  H1l [160,192)M fp8 : D1 out, D2/D3 in
    //   WvT (2MB bf16) transient in H1g slot pre-D1.
    //   X [192,208)M  Y [208,224)M fp8 : prep out, D1 in, D3 rewrite, D45 in;
    //     inside OUT2 region, written by finalize only after D45.
    //   D45 (EPI=4) writes bf16 P at the head of each O1 row [0,192)M;
    //   finalize reads P (regs), barriers, overwrites O1 row.
    bf16_t* Ug  = (bf16_t*)((char*)d_out + (64u << 20));
    bf16_t* Ul  = (bf16_t*)((char*)d_out + (96u << 20));
    unsigned char* H1g = (unsigned char*)d_out + (128u << 20);
    unsigned char* H1l = H1g + (32u << 20);
    bf16_t* WvT = (bf16_t*)H1g;                          // transient, pre-D1
    unsigned char* X = (unsigned char*)d_out + (192u << 20);
    unsigned char* Y = X + (16u << 20);

    PrepArgs pa;
    pa.w[0] = Wgu1; pa.w[1] = Wgd1; pa.w[2] = Wlu1; pa.w[3] = Wld1;
    pa.w[4] = Wgu2; pa.w[5] = Wgd2; pa.w[6] = Wlu2; pa.w[7] = Wld2;
    pa.Wo = Wo; pa.Wv = Wv; pa.SG = SG; pa.SL = SL;
    pa.bgu1 = bgu1; pa.bgd1 = bgd1; pa.blu1 = blu1; pa.bld1 = bld1;
    pa.bv = bv; pa.bo = bo;
    pa.Wf8 = Wf8; pa.Wo_b = Wo_b; pa.WvT = WvT;
    pa.X = X; pa.Y = Y; pa.bb = bb; pa.bvo = bvo;

    prep<<<22800, 256, 0, stream>>>(pa);

    // Wvo = fp8(16 * Wo @ Wv)
    gemm_small_bt<<<dim3(8, 8), 256, 0, stream>>>(Wo_b, 1024, WvT, Wvo, 1024, 1024);

    unsigned char* Wg1   = Wf8;                          // [Wgu1;Wgd1] 2048x1024
    unsigned char* Wl1   = Wf8 + (size_t)2 * 1048576;    // [Wlu1;Wld1]
    unsigned char* Wgu2b = Wf8 + (size_t)4 * 1048576;
    unsigned char* Wgd2b = Wf8 + (size_t)5 * 1048576;
    unsigned char* Wlu2b = Wf8 + (size_t)6 * 1048576;
    unsigned char* Wld2b = Wf8 + (size_t)7 * 1048576;

    // D1: h1 = relu([X;Y] @ [W?u1;W?d1]^T + b) -> fp8. N=2048 per half.
    gemm128_f8<0><<<4096, 256, 0, stream>>>(X, Y, 1024, Wg1, Wl1, bb, bb + 2048,
                                            nullptr, nullptr, H1g, H1l, 2048, 1024, 16, 128, 32);
    // D2: U = h1[:, :1024] @ W?u2^T + b -> bf16 (gate pre-act)
    gemm128_f8<1><<<2048, 256, 0, stream>>>(H1g, H1l, 2048, Wgu2b, Wlu2b, bgu2, blu2,
                                            nullptr, nullptr, Ug, Ul, 1024, 1024, 8, 128, 16);
    // D3: s? = sigmoid(U) * (h1[:, 1024:] @ W?d2^T + b) -> fp8 into X, Y
    gemm128_f8<2><<<2048, 256, 0, stream>>>(H1g + 1024, H1l + 1024, 2048, Wgd2b, Wld2b,
                                            bgd2, bld2, Ug, Ul, X, Y, 1024, 1024, 8, 128, 16);
    // D45: pre-norm attn_out = [sg;sl] @ Wvo^T + bvo -> bf16 P in O1 rows
    gemm128_f8<4><<<2048, 256, 0, stream>>>(X, X, 1024, Wvo, Wvo, bvo, bvo,
                                            nullptr, nullptr, OUT1, OUT1, 6144, 1024, 8, 256, 8);

    finalize_topk<<<16384, 256, 0, stream>>>(OUT2, OUT3, VIS, OUT1);
}

// Round 12
// 380.625 us; speedup vs baseline: 1.6917x; 1.0155x over previous
//
#include <hip/hip_runtime.h>

typedef __bf16 bf16_t;
typedef __bf16 bf16x4 __attribute__((ext_vector_type(4)));
typedef __bf16 bf16x8 __attribute__((ext_vector_type(8)));
typedef float f32x4 __attribute__((ext_vector_type(4)));
typedef int i32x4v __attribute__((ext_vector_type(4)));
typedef int i32x8v __attribute__((ext_vector_type(8)));

#define GLL16(gp, lp) __builtin_amdgcn_global_load_lds( \
    (__attribute__((address_space(1))) void*)(gp),      \
    (__attribute__((address_space(3))) void*)(lp), 16, 0, 0)

__device__ inline unsigned char f32_to_fp8(float v)
{
    return (unsigned char)(__builtin_amdgcn_cvt_pk_fp8_f32(v, v, 0, false) & 0xff);
}

__device__ inline i32x8v join8(i32x4v a, i32x4v b)
{
    i32x8v r;
    r[0] = a[0]; r[1] = a[1]; r[2] = a[2]; r[3] = a[3];
    r[4] = b[0]; r[5] = b[1]; r[6] = b[2]; r[7] = b[3];
    return r;
}

// ---------------------------------------------------------------------------
// 128x128-tile MX-fp8 GEMM, m97 structure (r9-r11 verified), BK=128.
//   C[half][M,N] = epi(A[half][M,K] @ W[half][N,K]^T + bias[half])
// 256 threads (4 waves 2x2); 32 KiB LDS single-buffered; 2 barriers/K-tile;
// cross-block overlap covers the staging drain (m97/m114); 4 blocks/CU via
// single per-lane staging base + wave-uniform r-offsets (r11).
// MFMA: mfma_scale_f32_16x16x128_f8f6f4, fp8 e4m3 both operands.
// UNIFORM scales: A 2^0 (0x7F); weights stored fp8(16*W), B-scale 2^-4 (0x7B).
// Swizzle: 16B-granule XOR row&7 both-sides. Epilogue n-innermost.
// XCD windows: 8-byh x 4-c.
// EPI: 0 relu->fp8, 1 bias->fp8 (gate pre-act, r12), 2 sigmoid(u_fp8)*v->fp8,
//      3 bias->f32, 4 bias->bf16 interleaved into O1 rows (half h row r ->
//        (bf16*)O1 + r*6144 + h*1024)
// ---------------------------------------------------------------------------
template<int EPI>
__global__ __launch_bounds__(256, 4)
void gemm128_f8(const unsigned char* __restrict__ A0,
                const unsigned char* __restrict__ A1, int lda,
                const unsigned char* __restrict__ W0,
                const unsigned char* __restrict__ W1,
                const float* __restrict__ bias0, const float* __restrict__ bias1,
                const unsigned char* __restrict__ U0,
                const unsigned char* __restrict__ U1,
                void* __restrict__ C0v, void* __restrict__ C1v, int ldc,
                int K, int nbx, int nbyH, int ctot)
{
    __shared__ __attribute__((aligned(64))) unsigned char As[128 * 128];
    __shared__ __attribute__((aligned(64))) unsigned char Bs[128 * 128];

    const int t = threadIdx.x;
    const int w = t >> 6, l = t & 63;
    const int wr = w >> 1, wc = w & 1;        // 2 x 2 wave grid
    const int ro = l & 15, hi = l >> 4;
    const int sw = ro & 7;
    const int gA = (((hi << 1) ^ sw) * 16);   // first 16B granule byte offset

    // XCD-window remap (gridDim%8==0, nbyH%8==0, ctot%4==0)
    const int xcd   = blockIdx.x & 7;
    const int local = blockIdx.x >> 3;
    const int wpb   = ctot >> 2;
    const int win   = local >> 5;
    const int r5    = local & 31;
    const int strp  = win / wpb;
    const int wcn   = win - strp * wpb;
    const int byh   = xcd * (nbyH >> 3) + strp * 8 + (r5 >> 2);
    const int c     = wcn * 4 + (r5 & 3);
    const int sel   = (c >= nbx) ? 1 : 0;
    const int bx    = c - sel * nbx;

    const unsigned char* A    = sel ? A1 : A0;
    const unsigned char* W    = sel ? W1 : W0;
    const float*  bias = sel ? bias1 : bias0;
    const unsigned char* Up = sel ? U1 : U0;
    void*         Cp   = sel ? C1v : C0v;

    const unsigned char* Ab = A + (size_t)byh * 128 * lda;
    const unsigned char* Wb = W + (size_t)bx * 128 * K;

    // single per-lane staging base; r-offsets are wave-uniform (fold to SGPR)
    const int trow = t >> 3;
    const int cg   = (t & 7) ^ (trow & 7);    // inverse of ds_read swizzle
    const unsigned char* asrc = Ab + (size_t)trow * lda + cg * 16;
    const unsigned char* bsrc = Wb + (size_t)trow * K   + cg * 16;
    int koff = 0;

    f32x4 acc[4][4] = {};

    for (int kt = 0; kt < K; kt += 128) {
#pragma unroll
        for (int r = 0; r < 4; ++r) {
            GLL16(asrc + (size_t)r * 32 * lda + koff, &As[(r * 256 + w * 64) * 16]);
            GLL16(bsrc + (size_t)r * 32 * K   + koff, &Bs[(r * 256 + w * 64) * 16]);
        }
        koff += 128;
        __syncthreads();
        i32x8v bq[4];
#pragma unroll
        for (int n = 0; n < 4; ++n) {
            const unsigned char* bp = Bs + (wc * 64 + n * 16 + ro) * 128;
            bq[n] = join8(*(const i32x4v*)(bp + gA),
                          *(const i32x4v*)(bp + (gA ^ 16)));
        }
#pragma unroll
        for (int m = 0; m < 4; ++m) {
            const unsigned char* ap = As + (wr * 64 + m * 16 + ro) * 128;
            const i32x8v af = join8(*(const i32x4v*)(ap + gA),
                                    *(const i32x4v*)(ap + (gA ^ 16)));
#pragma unroll
            for (int n = 0; n < 4; ++n)
                acc[m][n] = __builtin_amdgcn_mfma_scale_f32_16x16x128_f8f6f4(
                    af, bq[n], acc[m][n], 0, 0,
                    0, 0x7F7F7F7F,      // A scale = 2^0
                    0, 0x7B7B7B7B);     // B scale = 2^-4 (weights stored x16)
        }
        __syncthreads();
    }

    // epilogue: C/D frag layout col=lane&15, row=(lane>>4)*4+j  [guide m89]
    const int rbase = byh * 128 + wr * 64 + (hi << 2);
    const int cbase = bx * 128 + wc * 64 + ro;
    float bc[4];
#pragma unroll
    for (int n = 0; n < 4; ++n) bc[n] = bias[cbase + n * 16];
#pragma unroll
    for (int m = 0; m < 4; ++m) {
#pragma unroll
        for (int j = 0; j < 4; ++j) {
            const int row = rbase + m * 16 + j;
            const size_t off = (size_t)row * ldc + cbase;
            bf16_t* pd = (bf16_t*)Cp + ((row >> 14) ? 1024 : 0)
                       + (size_t)(row & 16383) * 6144 + cbase;   // EPI=4 dest
#pragma unroll
            for (int n = 0; n < 4; ++n) {
                float v = acc[m][n][j] + bc[n];
                if (EPI == 0) v = fmaxf(v, 0.0f);
                if (EPI == 2) {
                    const float u = __builtin_amdgcn_cvt_f32_fp8(
                        (int)Up[off + n * 16], 0);
                    v *= 1.0f / (1.0f + __expf(-u));
                }
                if (EPI == 3)      ((float*)Cp)[off + n * 16] = v;
                else if (EPI == 4) pd[n * 16] = (bf16_t)v;
                else ((unsigned char*)Cp)[off + n * 16] = f32_to_fp8(v);
            }
        }
    }
}

// ---------------------------------------------------------------------------
// Small bf16 128x128-tile GEMM for the Wo@Wv compose; writes fp8(16*C).
// ---------------------------------------------------------------------------
__global__ __launch_bounds__(256, 2)
void gemm_small_bt(const bf16_t* __restrict__ A, int lda,
                   const bf16_t* __restrict__ W,
                   unsigned char* __restrict__ C, int ldc, int K)
{
    __shared__ bf16_t As[128 * 64];
    __shared__ bf16_t Bs[128 * 64];
    const int t = threadIdx.x;
    const int w = t >> 6, l = t & 63;
    const int wr = w >> 1, wc = w & 1;

    const bf16_t* Ab = A + (size_t)blockIdx.y * 128 * lda;
    const bf16_t* Wb = W + (size_t)blockIdx.x * 128 * K;

    const bf16_t* asrc[4];
    const bf16_t* bsrc[4];
#pragma unroll
    for (int r = 0; r < 4; ++r) {
        const int seg = r * 256 + t;
        asrc[r] = Ab + (size_t)(seg >> 3) * lda + (seg & 7) * 8;
        bsrc[r] = Wb + (size_t)(seg >> 3) * K   + (seg & 7) * 8;
    }

    f32x4 acc[4][4] = {};

    for (int kt = 0; kt < K; kt += 64) {
#pragma unroll
        for (int r = 0; r < 4; ++r) {
            GLL16(asrc[r], As + (r * 256 + w * 64) * 8);
            GLL16(bsrc[r], Bs + (r * 256 + w * 64) * 8);
            asrc[r] += 64;
            bsrc[r] += 64;
        }
        __syncthreads();
#pragma unroll
        for (int kk = 0; kk < 2; ++kk) {
            const int ro = l & 15;
            const int ko = kk * 32 + (l >> 4) * 8;
            bf16x8 af[4], bqv[4];
#pragma unroll
            for (int m = 0; m < 4; ++m)
                af[m] = *(const bf16x8*)(As + (wr * 64 + m * 16 + ro) * 64 + ko);
#pragma unroll
            for (int n = 0; n < 4; ++n)
                bqv[n] = *(const bf16x8*)(Bs + (wc * 64 + n * 16 + ro) * 64 + ko);
#pragma unroll
            for (int m = 0; m < 4; ++m)
#pragma unroll
                for (int n = 0; n < 4; ++n)
                    acc[m][n] = __builtin_amdgcn_mfma_f32_16x16x32_bf16(
                        af[m], bqv[n], acc[m][n], 0, 0, 0);
        }
        __syncthreads();
    }

    const int rbase = blockIdx.y * 128 + wr * 64 + ((l >> 4) << 2);
    const int cbase = blockIdx.x * 128 + wc * 64 + (l & 15);
#pragma unroll
    for (int m = 0; m < 4; ++m)
#pragma unroll
        for (int j = 0; j < 4; ++j) {
            const int row = rbase + m * 16 + j;
#pragma unroll
            for (int n = 0; n < 4; ++n)
                C[(size_t)row * ldc + cbase + n * 16] =
                    f32_to_fp8(acc[m][n][j] * 16.0f);
        }
}

// ---------------------------------------------------------------------------
// One merged prep dispatch (role by block range):
//  [0,4096)      : 8 MLP weights f32 -> fp8(16*w)
//  [4096,20480)  : SG/SL f32 -> fp8 (8192 blocks each)
//  [20480,21504) : Wo f32 -> bf16
//  [21504,21760) : Wv transpose+cast -> WvT bf16 (16x16 tiles of 64)
//  [21760,21776) : bias concat (g then l)
//  [21776,22800) : bvo[j] = dot(Wo[j,:], bv) + bo[j]
// ---------------------------------------------------------------------------
struct PrepArgs {
    const float* w[8];
    const float* Wo; const float* Wv;
    const float* SG; const float* SL;
    const float* bgu1; const float* bgd1;
    const float* blu1; const float* bld1;
    const float* bv;  const float* bo;
    unsigned char* Wf8; bf16_t* Wo_b; bf16_t* WvT;
    unsigned char* X; unsigned char* Y;
    float* bb; float* bvo;
};

__global__ __launch_bounds__(256)
void prep(PrepArgs a)
{
    __shared__ bf16_t tile[64][65];
    __shared__ float ws4[4];
    int b = blockIdx.x;
    const int t = threadIdx.x;

    if (b < 4096) {                                      // weights -> fp8(x16)
        const int region = b >> 9;
        const float* src = a.w[region];
        const size_t base = (size_t)(b & 511) * 2048 + t * 8;
        const float4 f0 = *(const float4*)(src + base);
        const float4 f1 = *(const float4*)(src + base + 4);
        int x = __builtin_amdgcn_cvt_pk_fp8_f32(f0.x * 16.f, f0.y * 16.f, 0, false);
        x     = __builtin_amdgcn_cvt_pk_fp8_f32(f0.z * 16.f, f0.w * 16.f, x, true);
        int y = __builtin_amdgcn_cvt_pk_fp8_f32(f1.x * 16.f, f1.y * 16.f, 0, false);
        y     = __builtin_amdgcn_cvt_pk_fp8_f32(f1.z * 16.f, f1.w * 16.f, y, true);
        *(int2*)(a.Wf8 + ((size_t)region << 20) + base) = make_int2(x, y);
        return;
    }
    b -= 4096;
    if (b < 16384) {                                     // SG/SL -> fp8
        const float* src = (b < 8192) ? a.SG : a.SL;
        unsigned char* dst = (b < 8192) ? a.X : a.Y;
        const size_t i = ((size_t)(b & 8191) * 256 + t) * 8;
        const float4 f0 = *(const float4*)(src + i);
        const float4 f1 = *(const float4*)(src + i + 4);
        int x = __builtin_amdgcn_cvt_pk_fp8_f32(f0.x, f0.y, 0, false);
        x     = __builtin_amdgcn_cvt_pk_fp8_f32(f0.z, f0.w, x, true);
        int y = __builtin_amdgcn_cvt_pk_fp8_f32(f1.x, f1.y, 0, false);
        y     = __builtin_amdgcn_cvt_pk_fp8_f32(f1.z, f1.w, y, true);
        *(int2*)(dst + i) = make_int2(x, y);
        return;
    }
    b -= 16384;
    if (b < 1024) {                                      // Wo -> bf16
        const size_t i = ((size_t)b * 256 + t) * 4;
        const float4 f = *(const float4*)(a.Wo + i);
        bf16x4 h = {(bf16_t)f.x, (bf16_t)f.y, (bf16_t)f.z, (bf16_t)f.w};
        *(bf16x4*)(a.Wo_b + i) = h;
        return;
    }
    b -= 1024;
    if (b < 256) {                                       // Wv transpose
        const int bm = (b >> 4) * 64, bk = (b & 15) * 64;
#pragma unroll
        for (int s = 0; s < 4; ++s) {
            const int r = s * 16 + (t >> 4);
            const int c = (t & 15) * 4;
            const float4 f = *(const float4*)(a.Wv + (size_t)(bm + r) * 1024 + bk + c);
            tile[r][c] = (bf16_t)f.x; tile[r][c + 1] = (bf16_t)f.y;
            tile[r][c + 2] = (bf16_t)f.z; tile[r][c + 3] = (bf16_t)f.w;
        }
        __syncthreads();
#pragma unroll
        for (int s = 0; s < 4; ++s) {
            const int k = s * 16 + (t >> 4);
            const int m = (t & 15) * 4;
            bf16x4 v = {tile[m][k], tile[m + 1][k], tile[m + 2][k], tile[m + 3][k]};
            *(bf16x4*)(a.WvT + (size_t)(bk + k) * 1024 + bm + m) = v;
        }
        return;
    }
    b -= 256;
    if (b < 16) {                                        // bias concat
        const float* pa = (b < 8) ? a.bgu1 : a.blu1;
        const float* pb = (b < 8) ? a.bgd1 : a.bld1;
        float* dst = a.bb + ((b < 8) ? 0 : 2048);
        const int i = (b & 7) * 256 + t;
        if (i < 1024) dst[i] = pa[i];
        else dst[i] = pb[i - 1024];
        return;
    }
    b -= 16;
    {                                                    // bias_compose, j = b
        const float* wr = a.Wo + (size_t)b * 1024;
        float s = 0.0f;
#pragma unroll
        for (int i = 0; i < 4; ++i) s += wr[t + i * 256] * a.bv[t + i * 256];
#pragma unroll
        for (int o = 32; o > 0; o >>= 1) s += __shfl_down(s, o);
        if ((t & 63) == 0) ws4[t >> 6] = s;
        __syncthreads();
        if (t == 0) a.bvo[b] = ws4[0] + ws4[1] + ws4[2] + ws4[3] + a.bo[b];
    }
}

// ---------------------------------------------------------------------------
// One block per row. Inputs: P (bf16 pre-norm, interleaved at the head of
// this row's O1 slot). Reads P into registers, barriers, then: dual l2norm +
// sigmoid gate + exact top-80 radix select with EARLY EXIT (r12): when the
// boundary bin's count equals the remaining k, keep-set = {masked prefix >=
// pref} is provably the exact top-k (all value-ties at the boundary are
// included, so the lowest-index tie rule is vacuously satisfied); typical
// data exits after 2 of 4 passes, skipping the tie prefix-scan entirely.
// ---------------------------------------------------------------------------
__global__ __launch_bounds__(256)
void finalize_topk(float* __restrict__ OUT2, float* __restrict__ OUT3,
                   const float* __restrict__ VIS, float* __restrict__ O1)
{
    const int row = blockIdx.x, t = threadIdx.x;
    __shared__ int bins[256];
    __shared__ float wred[8];
    __shared__ int wsum[4];
    __shared__ int s_sel, s_kk, s_done;

    float* o1r = O1 + (size_t)row * 3072;
    const bf16_t* prow = (const bf16_t*)o1r;
    float av[4], lv[4];
    {
        const bf16x4 pg = *(const bf16x4*)(prow + t * 4);
        const bf16x4 pl = *(const bf16x4*)(prow + 1024 + t * 4);
#pragma unroll
        for (int j = 0; j < 4; ++j) { av[j] = (float)pg[j]; lv[j] = (float)pl[j]; }
    }
    __syncthreads();   // all P reads complete before o1r is overwritten

    float sa = 0.0f, sb = 0.0f;
#pragma unroll
    for (int j = 0; j < 4; ++j) { sa += av[j] * av[j]; sb += lv[j] * lv[j]; }
#pragma unroll
    for (int o = 32; o > 0; o >>= 1) {
        sa += __shfl_down(sa, o);
        sb += __shfl_down(sb, o);
    }
    if ((t & 63) == 0) { wred[t >> 6] = sa; wred[4 + (t >> 6)] = sb; }
    __syncthreads();
    const float sca = 1.0f / fmaxf(sqrtf(wred[0] + wred[1] + wred[2] + wred[3]), 1e-12f);
    const float scl = 1.0f / fmaxf(sqrtf(wred[4] + wred[5] + wred[6] + wred[7]), 1e-12f);

    float fv[4], f2v[4];
    unsigned ab[4];
#pragma unroll
    for (int j = 0; j < 4; ++j) {
        const float f2 = lv[j] * scl;
        const float f1 = av[j] * sca;
        const float fin = f2 / (1.0f + __expf(-f1));   // sigmoid(f1)*f2
        f2v[j] = f2; fv[j] = fin;
        ab[j] = __float_as_uint(fin) & 0x7fffffffu;
    }
    *(float4*)(OUT3 + (size_t)row * 1024 + t * 4) =
        make_float4(f2v[0], f2v[1], f2v[2], f2v[3]);
    *(float4*)(OUT2 + (size_t)row * 1024 + t * 4) =
        make_float4(fv[0], fv[1], fv[2], fv[3]);

    const float* vr = VIS + (size_t)row * 2048;
    *(float4*)(o1r + t * 4)        = *(const float4*)(vr + t * 4);
    *(float4*)(o1r + 1024 + t * 4) = *(const float4*)(vr + 1024 + t * 4);

    // --- radix select with early exit ---
    unsigned pref = 0u, msk = 0u;
    int kk = 80;
    bool early = false;
    for (int bp = 3; bp >= 0; --bp) {
        bins[t] = 0;
        __syncthreads();
#pragma unroll
        for (int j = 0; j < 4; ++j)
            if ((ab[j] & msk) == pref)
                atomicAdd(&bins[(ab[j] >> (bp * 8)) & 255], 1);
        __syncthreads();
        const int x = bins[t];
        int p = x;
#pragma unroll
        for (int o = 1; o < 64; o <<= 1) {
            const int y = __shfl_up(p, o);
            if ((t & 63) >= o) p += y;
        }
        if ((t & 63) == 63) wsum[t >> 6] = p;
        __syncthreads();
        const int tot = wsum[0] + wsum[1] + wsum[2] + wsum[3];
        int off = 0;
        if ((t >> 6) > 0) off += wsum[0];
        if ((t >> 6) > 1) off += wsum[1];
        if ((t >> 6) > 2) off += wsum[2];
        p += off;                              // inclusive prefix over 256
        const int Sme = tot - p + x;           // suffix sum incl. bin t
        const int Snx = tot - p;               // suffix sum from bin t+1
        if (Sme >= kk && Snx < kk) {
            s_sel = t; s_kk = kk - Snx; s_done = ((kk - Snx) == x) ? 1 : 0;
        }
        __syncthreads();
        pref |= (unsigned)s_sel << (bp * 8);
        msk  |= 0xFFu << (bp * 8);
        kk = s_kk;
        if (s_done) { early = true; break; }   // boundary bin fully consumed
        __syncthreads();
    }

    if (early) {
        // exact top-kk: masked prefix >= pref (all boundary ties kept)
#pragma unroll
        for (int j = 0; j < 4; ++j) {
            const bool kp = ((ab[j] & msk) >= pref);
            o1r[2048 + t * 4 + j] = kp ? fv[j] : 0.0f;
        }
        return;
    }

    // stable tie-break: keep first kk elements equal to threshold (index order)
    int ec = 0;
#pragma unroll
    for (int j = 0; j < 4; ++j) ec += (ab[j] == pref) ? 1 : 0;
    int pe = ec;
#pragma unroll
    for (int o = 1; o < 64; o <<= 1) {
        const int y = __shfl_up(pe, o);
        if ((t & 63) >= o) pe += y;
    }
    if ((t & 63) == 63) wsum[t >> 6] = pe;
    __syncthreads();
    int off2 = 0;
    if ((t >> 6) > 0) off2 += wsum[0];
    if ((t >> 6) > 1) off2 += wsum[1];
    if ((t >> 6) > 2) off2 += wsum[2];
    int excl = pe + off2 - ec;
#pragma unroll
    for (int j = 0; j < 4; ++j) {
        const bool eq = (ab[j] == pref);
        const bool kp = (ab[j] > pref) || (eq && (excl < kk));
        o1r[2048 + t * 4 + j] = kp ? fv[j] : 0.0f;
        if (eq) ++excl;
    }
}

// ---------------------------------------------------------------------------
extern "C" void kernel_launch(void* const* d_in, const int* in_sizes, int n_in,
                              void* d_out, int out_size, void* d_ws, size_t ws_size,
                              hipStream_t stream)
{
    const float* SG   = (const float*)d_in[0];
    const float* SL   = (const float*)d_in[1];
    const float* VIS  = (const float*)d_in[2];
    const float* Wgu1 = (const float*)d_in[3];
    const float* bgu1 = (const float*)d_in[4];
    const float* Wgu2 = (const float*)d_in[5];  const float* bgu2 = (const float*)d_in[6];
    const float* Wgd1 = (const float*)d_in[7];  const float* bgd1 = (const float*)d_in[8];
    const float* Wgd2 = (const float*)d_in[9];  const float* bgd2 = (const float*)d_in[10];
    const float* Wlu1 = (const float*)d_in[11]; const float* blu1 = (const float*)d_in[12];
    const float* Wlu2 = (const float*)d_in[13]; const float* blu2 = (const float*)d_in[14];
    const float* Wld1 = (const float*)d_in[15]; const float* bld1 = (const float*)d_in[16];
    const float* Wld2 = (const float*)d_in[17]; const float* bld2 = (const float*)d_in[18];
    const float* Wo   = (const float*)d_in[19]; const float* bo   = (const float*)d_in[20];
    const float* Win  = (const float*)d_in[21]; const float* bin_ = (const float*)d_in[22];
    const float* Wv = Win + (size_t)2 * 1024 * 1024;   // Win[2E:]
    const float* bv = bin_ + 2048;

    float* OUT1 = (float*)d_out;                         // B x 3072
    float* OUT2 = OUT1 + (size_t)16384 * 3072;           // B x 1024 (final)
    float* OUT3 = OUT2 + (size_t)16384 * 1024;           // B x 1024 (f2)

    // ws: fp8 weights (8 MLP, x16) + bf16 Wo + fp8 Wvo(x16) + biases (~12 MB)
    char* ws = (char*)d_ws;
    unsigned char* Wf8 = (unsigned char*)ws;             // [0, 8M)
    bf16_t* Wo_b = (bf16_t*)(ws + (8u << 20));           // [8M, 10M)
    unsigned char* Wvo = (unsigned char*)(ws + (10u << 20)); // [10M, 11M)
    float* bb  = (float*)(ws + (11u << 20));             // 4096 f32
    float* bvo = bb + 4096;                              // 1024 f32

    // scratch inside d_out (320 MiB), lifetime-checked (r10/r11 layout):
    //   Ug [64,80)M  Ul [96,112)M fp8 (r12) : D2 out, D3 in
    //   H1g [128,160)M  H1l [160,192)M fp8 : D1 out, D2/D3 in
    //   WvT (2MB bf16) transient in H1g slot pre-D1.
    //   X [192,208)M  Y [208,224)M fp8 : prep out, D1 in, D3 rewrite, D45 in;
    //     inside OUT2 region, written by finalize only after D45.
    //   D45 (EPI=4) writes bf16 P at the head of each O1 row [0,192)M;
    //   finalize reads P (regs), barriers, overwrites O1 row.
    unsigned char* Ug = (unsigned char*)d_out + (64u << 20);
    unsigned char* Ul = (unsigned char*)d_out + (96u << 20);
    unsigned char* H1g = (unsigned char*)d_out + (128u << 20);
    unsigned char* H1l = H1g + (32u << 20);
    bf16_t* WvT = (bf16_t*)H1g;                          // transient, pre-D1
    unsigned char* X = (unsigned char*)d_out + (192u << 20);
    unsigned char* Y = X + (16u << 20);

    PrepArgs pa;
    pa.w[0] = Wgu1; pa.w[1] = Wgd1; pa.w[2] = Wlu1; pa.w[3] = Wld1;
    pa.w[4] = Wgu2; pa.w[5] = Wgd2; pa.w[6] = Wlu2; pa.w[7] = Wld2;
    pa.Wo = Wo; pa.Wv = Wv; pa.SG = SG; pa.SL = SL;
    pa.bgu1 = bgu1; pa.bgd1 = bgd1; pa.blu1 = blu1; pa.bld1 = bld1;
    pa.bv = bv; pa.bo = bo;
    pa.Wf8 = Wf8; pa.Wo_b = Wo_b; pa.WvT = WvT;
    pa.X = X; pa.Y = Y; pa.bb = bb; pa.bvo = bvo;

    prep<<<22800, 256, 0, stream>>>(pa);

    // Wvo = fp8(16 * Wo @ Wv)
    gemm_small_bt<<<dim3(8, 8), 256, 0, stream>>>(Wo_b, 1024, WvT, Wvo, 1024, 1024);

    unsigned char* Wg1   = Wf8;                          // [Wgu1;Wgd1] 2048x1024
    unsigned char* Wl1   = Wf8 + (size_t)2 * 1048576;    // [Wlu1;Wld1]
    unsigned char* Wgu2b = Wf8 + (size_t)4 * 1048576;
    unsigned char* Wgd2b = Wf8 + (size_t)5 * 1048576;
    unsigned char* Wlu2b = Wf8 + (size_t)6 * 1048576;
    unsigned char* Wld2b = Wf8 + (size_t)7 * 1048576;

    // D1: h1 = relu([X;Y] @ [W?u1;W?d1]^T + b) -> fp8. N=2048 per half.
    gemm128_f8<0><<<4096, 256, 0, stream>>>(X, Y, 1024, Wg1, Wl1, bb, bb + 2048,
                                            nullptr, nullptr, H1g, H1l, 2048, 1024, 16, 128, 32);
    // D2: U = h1[:, :1024] @ W?u2^T + b -> fp8 (gate pre-act, r12)
    gemm128_f8<1><<<2048, 256, 0, stream>>>(H1g, H1l, 2048, Wgu2b, Wlu2b, bgu2, blu2,
                                            nullptr, nullptr, Ug, Ul, 1024, 1024, 8, 128, 16);
    // D3: s? = sigmoid(U_fp8) * (h1[:, 1024:] @ W?d2^T + b) -> fp8 into X, Y
    gemm128_f8<2><<<2048, 256, 0, stream>>>(H1g + 1024, H1l + 1024, 2048, Wgd2b, Wld2b,
                                            bgd2, bld2, Ug, Ul, X, Y, 1024, 1024, 8, 128, 16);
    // D45: pre-norm attn_out = [sg;sl] @ Wvo^T + bvo -> bf16 P in O1 rows
    gemm128_f8<4><<<2048, 256, 0, stream>>>(X, X, 1024, Wvo, Wvo, bvo, bvo,
                                            nullptr, nullptr, OUT1, OUT1, 6144, 1024, 8, 256, 8);

    finalize_topk<<<16384, 256, 0, stream>>>(OUT2, OUT3, VIS, OUT1);
}

// Round 13
// 350.658 us; speedup vs baseline: 1.8363x; 1.0855x over previous
//
#include <hip/hip_runtime.h>

typedef __bf16 bf16_t;
typedef __bf16 bf16x4 __attribute__((ext_vector_type(4)));
typedef __bf16 bf16x8 __attribute__((ext_vector_type(8)));
typedef float f32x4 __attribute__((ext_vector_type(4)));
typedef int i32x4v __attribute__((ext_vector_type(4)));
typedef int i32x8v __attribute__((ext_vector_type(8)));

#define GLL16(gp, lp) __builtin_amdgcn_global_load_lds( \
    (__attribute__((address_space(1))) void*)(gp),      \
    (__attribute__((address_space(3))) void*)(lp), 16, 0, 0)

__device__ inline unsigned char f32_to_fp8(float v)
{
    return (unsigned char)(__builtin_amdgcn_cvt_pk_fp8_f32(v, v, 0, false) & 0xff);
}

__device__ inline i32x8v join8(i32x4v a, i32x4v b)
{
    i32x8v r;
    r[0] = a[0]; r[1] = a[1]; r[2] = a[2]; r[3] = a[3];
    r[4] = b[0]; r[5] = b[1]; r[6] = b[2]; r[7] = b[3];
    return r;
}

// ---------------------------------------------------------------------------
// 128x128-tile MX-fp8 GEMM, m97 structure (r9-r12 verified), BK=128.
//   C[half][M,N] = epi(A[half][M,K] @ W[half][N,K]^T + bias[half])
// 256 threads (4 waves 2x2); 32 KiB LDS single-buffered; 2 barriers/K-tile;
// cross-block overlap covers the staging drain (m97/m114); 4 blocks/CU via
// single per-lane staging base + wave-uniform r-offsets (r11).
// MFMA: mfma_scale_f32_16x16x128_f8f6f4, fp8 e4m3 both operands.
// UNIFORM scales: A 2^0 (0x7F); weights stored fp8(16*W), B-scale 2^-4 (0x7B).
// Swizzle: 16B-granule XOR row&7 both-sides. Epilogue n-innermost.
// XCD windows: 8-byh x 4-c.
// EPI: 0 relu->fp8, 1 bias->fp8 (gate pre-act), 2 sigmoid(u_fp8)*v->fp8,
//      3 bias->f32, 4 bias->bf16 interleaved into O1 rows (half h row r ->
//        (bf16*)O1 + r*6144 + h*1024)
// ---------------------------------------------------------------------------
template<int EPI>
__global__ __launch_bounds__(256, 4)
void gemm128_f8(const unsigned char* __restrict__ A0,
                const unsigned char* __restrict__ A1, int lda,
                const unsigned char* __restrict__ W0,
                const unsigned char* __restrict__ W1,
                const float* __restrict__ bias0, const float* __restrict__ bias1,
                const unsigned char* __restrict__ U0,
                const unsigned char* __restrict__ U1,
                void* __restrict__ C0v, void* __restrict__ C1v, int ldc,
                int K, int nbx, int nbyH, int ctot)
{
    __shared__ __attribute__((aligned(64))) unsigned char As[128 * 128];
    __shared__ __attribute__((aligned(64))) unsigned char Bs[128 * 128];

    const int t = threadIdx.x;
    const int w = t >> 6, l = t & 63;
    const int wr = w >> 1, wc = w & 1;        // 2 x 2 wave grid
    const int ro = l & 15, hi = l >> 4;
    const int sw = ro & 7;
    const int gA = (((hi << 1) ^ sw) * 16);   // first 16B granule byte offset

    // XCD-window remap (gridDim%8==0, nbyH%8==0, ctot%4==0)
    const int xcd   = blockIdx.x & 7;
    const int local = blockIdx.x >> 3;
    const int wpb   = ctot >> 2;
    const int win   = local >> 5;
    const int r5    = local & 31;
    const int strp  = win / wpb;
    const int wcn   = win - strp * wpb;
    const int byh   = xcd * (nbyH >> 3) + strp * 8 + (r5 >> 2);
    const int c     = wcn * 4 + (r5 & 3);
    const int sel   = (c >= nbx) ? 1 : 0;
    const int bx    = c - sel * nbx;

    const unsigned char* A    = sel ? A1 : A0;
    const unsigned char* W    = sel ? W1 : W0;
    const float*  bias = sel ? bias1 : bias0;
    const unsigned char* Up = sel ? U1 : U0;
    void*         Cp   = sel ? C1v : C0v;

    const unsigned char* Ab = A + (size_t)byh * 128 * lda;
    const unsigned char* Wb = W + (size_t)bx * 128 * K;

    // single per-lane staging base; r-offsets are wave-uniform (fold to SGPR)
    const int trow = t >> 3;
    const int cg   = (t & 7) ^ (trow & 7);    // inverse of ds_read swizzle
    const unsigned char* asrc = Ab + (size_t)trow * lda + cg * 16;
    const unsigned char* bsrc = Wb + (size_t)trow * K   + cg * 16;
    int koff = 0;

    f32x4 acc[4][4] = {};

    for (int kt = 0; kt < K; kt += 128) {
#pragma unroll
        for (int r = 0; r < 4; ++r) {
            GLL16(asrc + (size_t)r * 32 * lda + koff, &As[(r * 256 + w * 64) * 16]);
            GLL16(bsrc + (size_t)r * 32 * K   + koff, &Bs[(r * 256 + w * 64) * 16]);
        }
        koff += 128;
        __syncthreads();
        i32x8v bq[4];
#pragma unroll
        for (int n = 0; n < 4; ++n) {
            const unsigned char* bp = Bs + (wc * 64 + n * 16 + ro) * 128;
            bq[n] = join8(*(const i32x4v*)(bp + gA),
                          *(const i32x4v*)(bp + (gA ^ 16)));
        }
#pragma unroll
        for (int m = 0; m < 4; ++m) {
            const unsigned char* ap = As + (wr * 64 + m * 16 + ro) * 128;
            const i32x8v af = join8(*(const i32x4v*)(ap + gA),
                                    *(const i32x4v*)(ap + (gA ^ 16)));
#pragma unroll
            for (int n = 0; n < 4; ++n)
                acc[m][n] = __builtin_amdgcn_mfma_scale_f32_16x16x128_f8f6f4(
                    af, bq[n], acc[m][n], 0, 0,
                    0, 0x7F7F7F7F,      // A scale = 2^0
                    0, 0x7B7B7B7B);     // B scale = 2^-4 (weights stored x16)
        }
        __syncthreads();
    }

    // epilogue: C/D frag layout col=lane&15, row=(lane>>4)*4+j  [guide m89]
    const int rbase = byh * 128 + wr * 64 + (hi << 2);
    const int cbase = bx * 128 + wc * 64 + ro;
    float bc[4];
#pragma unroll
    for (int n = 0; n < 4; ++n) bc[n] = bias[cbase + n * 16];
#pragma unroll
    for (int m = 0; m < 4; ++m) {
#pragma unroll
        for (int j = 0; j < 4; ++j) {
            const int row = rbase + m * 16 + j;
            const size_t off = (size_t)row * ldc + cbase;
            bf16_t* pd = (bf16_t*)Cp + ((row >> 14) ? 1024 : 0)
                       + (size_t)(row & 16383) * 6144 + cbase;   // EPI=4 dest
#pragma unroll
            for (int n = 0; n < 4; ++n) {
                float v = acc[m][n][j] + bc[n];
                if (EPI == 0) v = fmaxf(v, 0.0f);
                if (EPI == 2) {
                    const float u = __builtin_amdgcn_cvt_f32_fp8(
                        (int)Up[off + n * 16], 0);
                    v *= 1.0f / (1.0f + __expf(-u));
                }
                if (EPI == 3)      ((float*)Cp)[off + n * 16] = v;
                else if (EPI == 4) pd[n * 16] = (bf16_t)v;
                else ((unsigned char*)Cp)[off + n * 16] = f32_to_fp8(v);
            }
        }
    }
}

// ---------------------------------------------------------------------------
// One merged prep dispatch (role by block range; compose FIRST so its ~6 us
// of MFMA work hides under the 34 us of BW-bound cast blocks):
//  [0,64)        : Wvo = fp8(16 * Wo @ Wv), self-contained (raw f32 inputs)
//  [64,4160)     : 8 MLP weights f32 -> fp8(16*w)
//  [4160,20544)  : SG/SL f32 -> fp8 (8192 blocks each)
//  [20544,20560) : bias concat (g then l)
//  [20560,21584) : bvo[j] = dot(Wo[j,:], bv) + bo[j]
// ---------------------------------------------------------------------------
struct PrepArgs {
    const float* w[8];
    const float* Wo; const float* Wv;
    const float* SG; const float* SL;
    const float* bgu1; const float* bgd1;
    const float* blu1; const float* bld1;
    const float* bv;  const float* bo;
    unsigned char* Wf8; unsigned char* Wvo;
    unsigned char* X; unsigned char* Y;
    float* bb; float* bvo;
};

__global__ __launch_bounds__(256)
void prep(PrepArgs a)
{
    // compose staging: AsC padded [128][72] (conflict-free b128 reads);
    // BsC stored [64 m][128 k] (coalesced writes; u16 column gathers <=4-way)
    __shared__ bf16_t AsC[128 * 72];
    __shared__ bf16_t BsC[64 * 128];
    __shared__ float ws4[4];
    int b = blockIdx.x;
    const int t = threadIdx.x;

    if (b < 64) {                                        // Wvo compose
        const int by = b >> 3, bx = b & 7;
        const int n0 = by * 128, k0 = bx * 128;
        const int w = t >> 6, l = t & 63;
        const int wr = w >> 1, wc = w & 1;
        const int ro = l & 15, hi = l >> 4;
        f32x4 acc[4][4] = {};
        for (int mt = 0; mt < 1024; mt += 64) {
            // stage A: Wo[n0+row][mt+col] -> AsC[row][col]
#pragma unroll
            for (int r = 0; r < 8; ++r) {
                const int row = r * 16 + (t >> 4);
                const int col = (t & 15) * 4;
                const f32x4 f = *(const f32x4*)(a.Wo + (size_t)(n0 + row) * 1024 + mt + col);
                bf16x4 h = {(bf16_t)f[0], (bf16_t)f[1], (bf16_t)f[2], (bf16_t)f[3]};
                *(bf16x4*)(AsC + row * 72 + col) = h;
            }
            // stage B: Wv[mt+mr][k0+kc] -> BsC[mr][kc]
#pragma unroll
            for (int r = 0; r < 8; ++r) {
                const int mr = r * 8 + (t >> 5);
                const int kc = (t & 31) * 4;
                const f32x4 f = *(const f32x4*)(a.Wv + (size_t)(mt + mr) * 1024 + k0 + kc);
                bf16x4 h = {(bf16_t)f[0], (bf16_t)f[1], (bf16_t)f[2], (bf16_t)f[3]};
                *(bf16x4*)(BsC + mr * 128 + kc) = h;
            }
            __syncthreads();
#pragma unroll
            for (int kk = 0; kk < 2; ++kk) {
                const int ko = kk * 32 + hi * 8;
                bf16x8 af[4], bq[4];
#pragma unroll
                for (int m = 0; m < 4; ++m)
                    af[m] = *(const bf16x8*)(AsC + (wr * 64 + m * 16 + ro) * 72 + ko);
#pragma unroll
                for (int n = 0; n < 4; ++n) {
                    const int j = wc * 64 + n * 16 + ro;
#pragma unroll
                    for (int e = 0; e < 8; ++e)
                        bq[n][e] = BsC[(ko + e) * 128 + j];
                }
#pragma unroll
                for (int m = 0; m < 4; ++m)
#pragma unroll
                    for (int n = 0; n < 4; ++n)
                        acc[m][n] = __builtin_amdgcn_mfma_f32_16x16x32_bf16(
                            af[m], bq[n], acc[m][n], 0, 0, 0);
            }
            __syncthreads();
        }
        const int rbase = n0 + wr * 64 + (hi << 2);
        const int cbase = k0 + wc * 64 + ro;
#pragma unroll
        for (int m = 0; m < 4; ++m)
#pragma unroll
            for (int j = 0; j < 4; ++j) {
                const int row = rbase + m * 16 + j;
#pragma unroll
                for (int n = 0; n < 4; ++n)
                    a.Wvo[(size_t)row * 1024 + cbase + n * 16] =
                        f32_to_fp8(acc[m][n][j] * 16.0f);
            }
        return;
    }
    b -= 64;
    if (b < 4096) {                                      // weights -> fp8(x16)
        const int region = b >> 9;
        const float* src = a.w[region];
        const size_t base = (size_t)(b & 511) * 2048 + t * 8;
        const f32x4 f0 = __builtin_nontemporal_load((const f32x4*)(src + base));
        const f32x4 f1 = __builtin_nontemporal_load((const f32x4*)(src + base + 4));
        int x = __builtin_amdgcn_cvt_pk_fp8_f32(f0[0] * 16.f, f0[1] * 16.f, 0, false);
        x     = __builtin_amdgcn_cvt_pk_fp8_f32(f0[2] * 16.f, f0[3] * 16.f, x, true);
        int y = __builtin_amdgcn_cvt_pk_fp8_f32(f1[0] * 16.f, f1[1] * 16.f, 0, false);
        y     = __builtin_amdgcn_cvt_pk_fp8_f32(f1[2] * 16.f, f1[3] * 16.f, y, true);
        *(int2*)(a.Wf8 + ((size_t)region << 20) + base) = make_int2(x, y);
        return;
    }
    b -= 4096;
    if (b < 16384) {                                     // SG/SL -> fp8
        const float* src = (b < 8192) ? a.SG : a.SL;
        unsigned char* dst = (b < 8192) ? a.X : a.Y;
        const size_t i = ((size_t)(b & 8191) * 256 + t) * 8;
        const f32x4 f0 = __builtin_nontemporal_load((const f32x4*)(src + i));
        const f32x4 f1 = __builtin_nontemporal_load((const f32x4*)(src + i + 4));
        int x = __builtin_amdgcn_cvt_pk_fp8_f32(f0[0], f0[1], 0, false);
        x     = __builtin_amdgcn_cvt_pk_fp8_f32(f0[2], f0[3], x, true);
        int y = __builtin_amdgcn_cvt_pk_fp8_f32(f1[0], f1[1], 0, false);
        y     = __builtin_amdgcn_cvt_pk_fp8_f32(f1[2], f1[3], y, true);
        *(int2*)(dst + i) = make_int2(x, y);
        return;
    }
    b -= 16384;
    if (b < 16) {                                        // bias concat
        const float* pa = (b < 8) ? a.bgu1 : a.blu1;
        const float* pb = (b < 8) ? a.bgd1 : a.bld1;
        float* dst = a.bb + ((b < 8) ? 0 : 2048);
        const int i = (b & 7) * 256 + t;
        if (i < 1024) dst[i] = pa[i];
        else dst[i] = pb[i - 1024];
        return;
    }
    b -= 16;
    {                                                    // bias_compose, j = b
        const float* wr = a.Wo + (size_t)b * 1024;
        float s = 0.0f;
#pragma unroll
        for (int i = 0; i < 4; ++i) s += wr[t + i * 256] * a.bv[t + i * 256];
#pragma unroll
        for (int o = 32; o > 0; o >>= 1) s += __shfl_down(s, o);
        if ((t & 63) == 0) ws4[t >> 6] = s;
        __syncthreads();
        if (t == 0) a.bvo[b] = ws4[0] + ws4[1] + ws4[2] + ws4[3] + a.bo[b];
    }
}

// ---------------------------------------------------------------------------
// One block per row. Inputs: P (bf16 pre-norm, interleaved at the head of
// this row's O1 slot). Reads P into registers, barriers, then: dual l2norm +
// sigmoid gate + exact top-80 radix select with early exit (r12) + O1 =
// [vis | sparse] + OUT2/OUT3. Streaming IO uses nontemporal hints (r13).
// ---------------------------------------------------------------------------
__global__ __launch_bounds__(256)
void finalize_topk(float* __restrict__ OUT2, float* __restrict__ OUT3,
                   const float* __restrict__ VIS, float* __restrict__ O1)
{
    const int row = blockIdx.x, t = threadIdx.x;
    __shared__ int bins[256];
    __shared__ float wred[8];
    __shared__ int wsum[4];
    __shared__ int s_sel, s_kk, s_done;

    float* o1r = O1 + (size_t)row * 3072;
    const bf16_t* prow = (const bf16_t*)o1r;
    float av[4], lv[4];
    {
        const bf16x4 pg = *(const bf16x4*)(prow + t * 4);
        const bf16x4 pl = *(const bf16x4*)(prow + 1024 + t * 4);
#pragma unroll
        for (int j = 0; j < 4; ++j) { av[j] = (float)pg[j]; lv[j] = (float)pl[j]; }
    }
    __syncthreads();   // all P reads complete before o1r is overwritten

    float sa = 0.0f, sb = 0.0f;
#pragma unroll
    for (int j = 0; j < 4; ++j) { sa += av[j] * av[j]; sb += lv[j] * lv[j]; }
#pragma unroll
    for (int o = 32; o > 0; o >>= 1) {
        sa += __shfl_down(sa, o);
        sb += __shfl_down(sb, o);
    }
    if ((t & 63) == 0) { wred[t >> 6] = sa; wred[4 + (t >> 6)] = sb; }
    __syncthreads();
    const float sca = 1.0f / fmaxf(sqrtf(wred[0] + wred[1] + wred[2] + wred[3]), 1e-12f);
    const float scl = 1.0f / fmaxf(sqrtf(wred[4] + wred[5] + wred[6] + wred[7]), 1e-12f);

    float fv[4], f2v[4];
    unsigned ab[4];
#pragma unroll
    for (int j = 0; j < 4; ++j) {
        const float f2 = lv[j] * scl;
        const float f1 = av[j] * sca;
        const float fin = f2 / (1.0f + __expf(-f1));   // sigmoid(f1)*f2
        f2v[j] = f2; fv[j] = fin;
        ab[j] = __float_as_uint(fin) & 0x7fffffffu;
    }
    {
        f32x4 v2 = {fv[0], fv[1], fv[2], fv[3]};
        f32x4 v3 = {f2v[0], f2v[1], f2v[2], f2v[3]};
        __builtin_nontemporal_store(v2, (f32x4*)(OUT2 + (size_t)row * 1024 + t * 4));
        __builtin_nontemporal_store(v3, (f32x4*)(OUT3 + (size_t)row * 1024 + t * 4));
    }

    const float* vr = VIS + (size_t)row * 2048;
    {
        const f32x4 a0 = __builtin_nontemporal_load((const f32x4*)(vr + t * 4));
        const f32x4 a1 = __builtin_nontemporal_load((const f32x4*)(vr + 1024 + t * 4));
        __builtin_nontemporal_store(a0, (f32x4*)(o1r + t * 4));
        __builtin_nontemporal_store(a1, (f32x4*)(o1r + 1024 + t * 4));
    }

    // --- radix select with early exit ---
    unsigned pref = 0u, msk = 0u;
    int kk = 80;
    bool early = false;
    for (int bp = 3; bp >= 0; --bp) {
        bins[t] = 0;
        __syncthreads();
#pragma unroll
        for (int j = 0; j < 4; ++j)
            if ((ab[j] & msk) == pref)
                atomicAdd(&bins[(ab[j] >> (bp * 8)) & 255], 1);
        __syncthreads();
        const int x = bins[t];
        int p = x;
#pragma unroll
        for (int o = 1; o < 64; o <<= 1) {
            const int y = __shfl_up(p, o);
            if ((t & 63) >= o) p += y;
        }
        if ((t & 63) == 63) wsum[t >> 6] = p;
        __syncthreads();
        const int tot = wsum[0] + wsum[1] + wsum[2] + wsum[3];
        int off = 0;
        if ((t >> 6) > 0) off += wsum[0];
        if ((t >> 6) > 1) off += wsum[1];
        if ((t >> 6) > 2) off += wsum[2];
        p += off;                              // inclusive prefix over 256
        const int Sme = tot - p + x;           // suffix sum incl. bin t
        const int Snx = tot - p;               // suffix sum from bin t+1
        if (Sme >= kk && Snx < kk) {
            s_sel = t; s_kk = kk - Snx; s_done = ((kk - Snx) == x) ? 1 : 0;
        }
        __syncthreads();
        pref |= (unsigned)s_sel << (bp * 8);
        msk  |= 0xFFu << (bp * 8);
        kk = s_kk;
        if (s_done) { early = true; break; }   // boundary bin fully consumed
        __syncthreads();
    }

    if (early) {
        // exact top-kk: masked prefix >= pref (all boundary ties kept)
#pragma unroll
        for (int j = 0; j < 4; ++j) {
            const bool kp = ((ab[j] & msk) >= pref);
            __builtin_nontemporal_store(kp ? fv[j] : 0.0f, o1r + 2048 + t * 4 + j);
        }
        return;
    }

    // stable tie-break: keep first kk elements equal to threshold (index order)
    int ec = 0;
#pragma unroll
    for (int j = 0; j < 4; ++j) ec += (ab[j] == pref) ? 1 : 0;
    int pe = ec;
#pragma unroll
    for (int o = 1; o < 64; o <<= 1) {
        const int y = __shfl_up(pe, o);
        if ((t & 63) >= o) pe += y;
    }
    if ((t & 63) == 63) wsum[t >> 6] = pe;
    __syncthreads();
    int off2 = 0;
    if ((t >> 6) > 0) off2 += wsum[0];
    if ((t >> 6) > 1) off2 += wsum[1];
    if ((t >> 6) > 2) off2 += wsum[2];
    int excl = pe + off2 - ec;
#pragma unroll
    for (int j = 0; j < 4; ++j) {
        const bool eq = (ab[j] == pref);
        const bool kp = (ab[j] > pref) || (eq && (excl < kk));
        __builtin_nontemporal_store(kp ? fv[j] : 0.0f, o1r + 2048 + t * 4 + j);
        if (eq) ++excl;
    }
}

// ---------------------------------------------------------------------------
extern "C" void kernel_launch(void* const* d_in, const int* in_sizes, int n_in,
                              void* d_out, int out_size, void* d_ws, size_t ws_size,
                              hipStream_t stream)
{
    const float* SG   = (const float*)d_in[0];
    const float* SL   = (const float*)d_in[1];
    const float* VIS  = (const float*)d_in[2];
    const float* Wgu1 = (const float*)d_in[3];
    const float* bgu1 = (const float*)d_in[4];
    const float* Wgu2 = (const float*)d_in[5];  const float* bgu2 = (const float*)d_in[6];
    const float* Wgd1 = (const float*)d_in[7];  const float* bgd1 = (const float*)d_in[8];
    const float* Wgd2 = (const float*)d_in[9];  const float* bgd2 = (const float*)d_in[10];
    const float* Wlu1 = (const float*)d_in[11]; const float* blu1 = (const float*)d_in[12];
    const float* Wlu2 = (const float*)d_in[13]; const float* blu2 = (const float*)d_in[14];
    const float* Wld1 = (const float*)d_in[15]; const float* bld1 = (const float*)d_in[16];
    const float* Wld2 = (const float*)d_in[17]; const float* bld2 = (const float*)d_in[18];
    const float* Wo   = (const float*)d_in[19]; const float* bo   = (const float*)d_in[20];
    const float* Win  = (const float*)d_in[21]; const float* bin_ = (const float*)d_in[22];
    const float* Wv = Win + (size_t)2 * 1024 * 1024;   // Win[2E:]
    const float* bv = bin_ + 2048;

    float* OUT1 = (float*)d_out;                         // B x 3072
    float* OUT2 = OUT1 + (size_t)16384 * 3072;           // B x 1024 (final)
    float* OUT3 = OUT2 + (size_t)16384 * 1024;           // B x 1024 (f2)

    // ws: fp8 weights (8 MLP, x16) + fp8 Wvo(x16) + biases (~9.1 MB)
    char* ws = (char*)d_ws;
    unsigned char* Wf8 = (unsigned char*)ws;             // [0, 8M)
    unsigned char* Wvo = (unsigned char*)(ws + (8u << 20)); // [8M, 9M)
    float* bb  = (float*)(ws + (9u << 20));              // 4096 f32
    float* bvo = bb + 4096;                              // 1024 f32

    // scratch inside d_out (320 MiB), lifetime-checked (r10-r12 layout):
    //   Ug [64,80)M  Ul [96,112)M fp8 : D2 out, D3 in
    //   H1g [128,160)M  H1l [160,192)M fp8 : D1 out, D2/D3 in
    //   X [192,208)M  Y [208,224)M fp8 : prep out, D1 in, D3 rewrite, D45 in;
    //     inside OUT2 region, written by finalize only after D45.
    //   D45 (EPI=4) writes bf16 P at the head of each O1 row [0,192)M;
    //   finalize reads P (regs), barriers, overwrites O1 row.
    unsigned char* Ug = (unsigned char*)d_out + (64u << 20);
    unsigned char* Ul = (unsigned char*)d_out + (96u << 20);
    unsigned char* H1g = (unsigned char*)d_out + (128u << 20);
    unsigned char* H1l = H1g + (32u << 20);
    unsigned char* X = (unsigned char*)d_out + (192u << 20);
    unsigned char* Y = X + (16u << 20);

    PrepArgs pa;
    pa.w[0] = Wgu1; pa.w[1] = Wgd1; pa.w[2] = Wlu1; pa.w[3] = Wld1;
    pa.w[4] = Wgu2; pa.w[5] = Wgd2; pa.w[6] = Wlu2; pa.w[7] = Wld2;
    pa.Wo = Wo; pa.Wv = Wv; pa.SG = SG; pa.SL = SL;
    pa.bgu1 = bgu1; pa.bgd1 = bgd1; pa.blu1 = blu1; pa.bld1 = bld1;
    pa.bv = bv; pa.bo = bo;
    pa.Wf8 = Wf8; pa.Wvo = Wvo;
    pa.X = X; pa.Y = Y; pa.bb = bb; pa.bvo = bvo;

    prep<<<21584, 256, 0, stream>>>(pa);

    unsigned char* Wg1   = Wf8;                          // [Wgu1;Wgd1] 2048x1024
    unsigned char* Wl1   = Wf8 + (size_t)2 * 1048576;    // [Wlu1;Wld1]
    unsigned char* Wgu2b = Wf8 + (size_t)4 * 1048576;
    unsigned char* Wgd2b = Wf8 + (size_t)5 * 1048576;
    unsigned char* Wlu2b = Wf8 + (size_t)6 * 1048576;
    unsigned char* Wld2b = Wf8 + (size_t)7 * 1048576;

    // D1: h1 = relu([X;Y] @ [W?u1;W?d1]^T + b) -> fp8. N=2048 per half.
    gemm128_f8<0><<<4096, 256, 0, stream>>>(X, Y, 1024, Wg1, Wl1, bb, bb + 2048,
                                            nullptr, nullptr, H1g, H1l, 2048, 1024, 16, 128, 32);
    // D2: U = h1[:, :1024] @ W?u2^T + b -> fp8 (gate pre-act)
    gemm128_f8<1><<<2048, 256, 0, stream>>>(H1g, H1l, 2048, Wgu2b, Wlu2b, bgu2, blu2,
                                            nullptr, nullptr, Ug, Ul, 1024, 1024, 8, 128, 16);
    // D3: s? = sigmoid(U_fp8) * (h1[:, 1024:] @ W?d2^T + b) -> fp8 into X, Y
    gemm128_f8<2><<<2048, 256, 0, stream>>>(H1g + 1024, H1l + 1024, 2048, Wgd2b, Wld2b,
                                            bgd2, bld2, Ug, Ul, X, Y, 1024, 1024, 8, 128, 16);
    // D45: pre-norm attn_out = [sg;sl] @ Wvo^T + bvo -> bf16 P in O1 rows
    gemm128_f8<4><<<2048, 256, 0, stream>>>(X, X, 1024, Wvo, Wvo, bvo, bvo,
                                            nullptr, nullptr, OUT1, OUT1, 6144, 1024, 8, 256, 8);

    finalize_topk<<<16384, 256, 0, stream>>>(OUT2, OUT3, VIS, OUT1);
}